// Round 2
// baseline (5579.279 us; speedup 1.0000x reference)
//
#include <hip/hip_runtime.h>
#include <cstdio>
#include <cstdint>

#define CDIV(a,b) (((a)+(b)-1)/(b))

static const int N   = 50000;   // nodes
static const int NE0 = 150000;  // edges w/o self loops
static const int NE  = 200000;  // edges with self loops
static const int H   = 10;      // heads
static const int F   = 78;      // per-head features
static const int C   = 780;     // H*F
static const int G   = 128;     // graphs
static const int CCH = 156;     // column chunk (2 heads)

// ---------------------------------------------------------------------------
// Generic tiled fp32 GEMM: C[M,Nn] = A[M,K] @ B[K,Nn] (+bias) (optional relu)
// Strided: A row-major lda, B row-major ldb, C row-major ldc.
// block 16x16 threads, 64x64 tile, 4x4 micro-tile, K-tile 16.
// ---------------------------------------------------------------------------
__global__ void gemm_tiled(const float* __restrict__ A, const float* __restrict__ B,
                           const float* __restrict__ bias, float* __restrict__ Cc,
                           int M, int Nn, int K, int lda, int ldb, int ldc, int relu)
{
    __shared__ float As[16][68];
    __shared__ float Bs[16][68];
    const int tx = threadIdx.x, ty = threadIdx.y;
    const int tid = ty * 16 + tx;
    const int bm = blockIdx.x * 64, bn = blockIdx.y * 64;

    float acc[4][4] = {};

    for (int k0 = 0; k0 < K; k0 += 16) {
        for (int i = tid; i < 64 * 16; i += 256) {
            int m = i >> 4, kk = i & 15;
            int gm = bm + m, gk = k0 + kk;
            As[kk][m] = (gm < M && gk < K) ? A[(size_t)gm * lda + gk] : 0.f;
        }
        for (int i = tid; i < 16 * 64; i += 256) {
            int kk = i >> 6, n = i & 63;
            int gk = k0 + kk, gn = bn + n;
            Bs[kk][n] = (gk < K && gn < Nn) ? B[(size_t)gk * ldb + gn] : 0.f;
        }
        __syncthreads();
#pragma unroll
        for (int kk = 0; kk < 16; kk++) {
            float4 a4 = *(const float4*)&As[kk][ty * 4];
            float4 b4 = *(const float4*)&Bs[kk][tx * 4];
            float a[4] = {a4.x, a4.y, a4.z, a4.w};
            float b[4] = {b4.x, b4.y, b4.z, b4.w};
#pragma unroll
            for (int i = 0; i < 4; i++)
#pragma unroll
                for (int j = 0; j < 4; j++)
                    acc[i][j] += a[i] * b[j];
        }
        __syncthreads();
    }

    for (int i = 0; i < 4; i++) {
        int gm = bm + ty * 4 + i;
        if (gm >= M) continue;
        for (int j = 0; j < 4; j++) {
            int gn = bn + tx * 4 + j;
            if (gn >= Nn) continue;
            float v = acc[i][j];
            if (bias) v += bias[gn];
            if (relu) v = fmaxf(v, 0.f);
            Cc[(size_t)gm * ldc + gn] = v;
        }
    }
}

// ---------------------------------------------------------------------------
// V_s[k,h] = sum_f W_gat[k, h*F+f] * att_src[h,f]  (78x10), same for V_d.
// Lets us compute attention logits directly from x without materializing h1.
// ---------------------------------------------------------------------------
__global__ void k_Vsd(const float* __restrict__ W_gat, const float* __restrict__ att_src,
                      const float* __restrict__ att_dst, float* __restrict__ V_s,
                      float* __restrict__ V_d)
{
    int idx = blockIdx.x * blockDim.x + threadIdx.x;
    if (idx >= F * H) return;
    int k = idx / H, h = idx % H;
    const float* wr = W_gat + (size_t)k * C + h * F;
    const float* as = att_src + h * F;
    const float* ad = att_dst + h * F;
    float s = 0.f, d = 0.f;
    for (int f = 0; f < F; f++) { float w = wr[f]; s += w * as[f]; d += w * ad[f]; }
    V_s[idx] = s; V_d[idx] = d;
}

// a_s[n,h] = sum_k x[n,k] * V_s[k,h]
__global__ void k_ascores(const float* __restrict__ x, const float* __restrict__ V_s,
                          const float* __restrict__ V_d, float* __restrict__ a_s,
                          float* __restrict__ a_d)
{
    __shared__ float Vs[F * H], Vd[F * H];
    int t = threadIdx.x;
    for (int i = t; i < F * H; i += 256) { Vs[i] = V_s[i]; Vd[i] = V_d[i]; }
    __syncthreads();
    int n = blockIdx.x * 256 + t;
    if (n >= N) return;
    const float* xr = x + (size_t)n * F;
    float accs[H] = {}, accd[H] = {};
    for (int k = 0; k < F; k++) {
        float xv = xr[k];
        const float* vs = &Vs[k * H];
        const float* vd = &Vd[k * H];
#pragma unroll
        for (int h = 0; h < H; h++) { accs[h] += xv * vs[h]; accd[h] += xv * vd[h]; }
    }
    for (int h = 0; h < H; h++) { a_s[n * H + h] = accs[h]; a_d[n * H + h] = accd[h]; }
}

// ---------------------------------------------------------------------------
// CSR build (edges include implicit self-loops: e in [NE0,NE) is node e-NE0)
// ---------------------------------------------------------------------------
__global__ void count_deg(const int* __restrict__ ei, int* __restrict__ deg)
{
    int e = blockIdx.x * blockDim.x + threadIdx.x;
    if (e >= NE) return;
    int d = (e < NE0) ? ei[NE0 + e] : (e - NE0);
    atomicAdd(&deg[d], 1);
}

__global__ void scan_int(const int* __restrict__ cnt, int* __restrict__ row_start, int n)
{
    __shared__ int partial[1024];
    int tid = threadIdx.x;
    int per = CDIV(n, 1024);
    int start = tid * per, end = min(start + per, n);
    int sum = 0;
    for (int i = start; i < end; i++) sum += cnt[i];
    partial[tid] = sum;
    __syncthreads();
    for (int off = 1; off < 1024; off *= 2) {
        int v = (tid >= off) ? partial[tid - off] : 0;
        __syncthreads();
        partial[tid] += v;
        __syncthreads();
    }
    int base = (tid > 0) ? partial[tid - 1] : 0;
    for (int i = start; i < end; i++) { row_start[i] = base; base += cnt[i]; }
    if (tid == 1023) row_start[n] = base;
}

__global__ void fill_csr(const int* __restrict__ ei, const int* __restrict__ row_start,
                         int* __restrict__ fill_cnt, int* __restrict__ edge_list)
{
    int e = blockIdx.x * blockDim.x + threadIdx.x;
    if (e >= NE) return;
    int d = (e < NE0) ? ei[NE0 + e] : (e - NE0);
    int pos = row_start[d] + atomicAdd(&fill_cnt[d], 1);
    edge_list[pos] = e;
}

__global__ void k_graph_cnt(const int* __restrict__ batch, int* __restrict__ gcnt)
{
    int n = blockIdx.x * blockDim.x + threadIdx.x;
    if (n >= N) return;
    atomicAdd(&gcnt[batch[n]], 1);
}

// ---------------------------------------------------------------------------
// GAT softmax stats per (dst node, head): online max + sum of exp
// ---------------------------------------------------------------------------
__global__ void k_softmax_stats(const int* __restrict__ ei, const int* __restrict__ row_start,
                                const int* __restrict__ edge_list,
                                const float* __restrict__ a_s, const float* __restrict__ a_d,
                                float* __restrict__ m_ns, float* __restrict__ s_ns)
{
    int idx = blockIdx.x * blockDim.x + threadIdx.x;
    if (idx >= N * H) return;
    int n = idx / H, h = idx % H;
    float ad = a_d[idx];
    int rs = row_start[n], re = row_start[n + 1];
    float m = -INFINITY, s = 0.f;
    for (int i = rs; i < re; i++) {
        int e = edge_list[i];
        int sr = (e < NE0) ? ei[e] : (e - NE0);
        float ev = a_s[sr * H + h] + ad;
        ev = (ev > 0.f) ? ev : 0.2f * ev;
        if (ev <= m) {
            s += expf(ev - m);
        } else {
            s = s * expf(m - ev) + 1.f;
            m = ev;
        }
    }
    m_ns[idx] = m;
    s_ns[idx] = s;
}

__global__ void k_alpha(const int* __restrict__ ei, const float* __restrict__ a_s,
                        const float* __restrict__ a_d, const float* __restrict__ m_ns,
                        const float* __restrict__ s_ns, float* __restrict__ alpha)
{
    int idx = blockIdx.x * blockDim.x + threadIdx.x;
    if (idx >= NE * H) return;
    int e = idx / H, h = idx % H;
    int sr = (e < NE0) ? ei[e] : (e - NE0);
    int ds = (e < NE0) ? ei[NE0 + e] : (e - NE0);
    float ev = a_s[sr * H + h] + a_d[ds * H + h];
    ev = (ev > 0.f) ? ev : 0.2f * ev;
    alpha[idx] = expf(ev - m_ns[ds * H + h]) / (s_ns[ds * H + h] + 1e-16f);
}

// ---------------------------------------------------------------------------
// GAT aggregation, one 156-column (2-head) chunk:
// gat_out[n, c0+cl] = relu( sum_e alpha[e,h]*h1c[src,cl] + b[c0+cl] )
// ---------------------------------------------------------------------------
__global__ void gat_agg_chunk(const float* __restrict__ h1c, const float* __restrict__ alpha,
                              const int* __restrict__ ei, const int* __restrict__ row_start,
                              const int* __restrict__ edge_list, const float* __restrict__ b_gat,
                              float* __restrict__ gat_out, int c0)
{
    int n = blockIdx.x;
    int cl = threadIdx.x;
    if (cl >= CCH) return;
    int cg = c0 + cl;
    int h = cg / F;
    int rs = row_start[n], re = row_start[n + 1];
    float acc = 0.f;
    for (int i = rs; i < re; i++) {
        int e = edge_list[i];
        int sr = (e < NE0) ? ei[e] : (e - NE0);
        acc += alpha[e * H + h] * h1c[(size_t)sr * CCH + cl];
    }
    gat_out[(size_t)n * C + cg] = fmaxf(acc + b_gat[cg], 0.f);
}

__global__ void k_dinv(const int* __restrict__ deg, float* __restrict__ dinv)
{
    int n = blockIdx.x * blockDim.x + threadIdx.x;
    if (n >= N) return;
    int d = deg[n];
    dinv[n] = (d > 0) ? 1.f / sqrtf((float)d) : 0.f;
}

// gcn_chunk[n,cl] = relu( dinv[n]*sum_e dinv[src]*h2c[src,cl] + b[c0+cl] )
__global__ void gcn_agg_chunk(const float* __restrict__ h2c, const float* __restrict__ dinv,
                              const int* __restrict__ ei, const int* __restrict__ row_start,
                              const int* __restrict__ edge_list, const float* __restrict__ b_gcn,
                              float* __restrict__ out, int c0)
{
    int n = blockIdx.x;
    int cl = threadIdx.x;
    if (cl >= CCH) return;
    float dn = dinv[n];
    int rs = row_start[n], re = row_start[n + 1];
    float acc = 0.f;
    for (int i = rs; i < re; i++) {
        int e = edge_list[i];
        int sr = (e < NE0) ? ei[e] : (e - NE0);
        acc += dinv[sr] * h2c[(size_t)sr * CCH + cl];
    }
    out[(size_t)n * CCH + cl] = fmaxf(acc * dn + b_gcn[c0 + cl], 0.f);
}

// max+mean pool of one 156-col chunk into gfeat[g, 0:780]=max, [780:1560]=mean
__global__ void k_pool_chunk(const float* __restrict__ hh, const int* __restrict__ gstart,
                             float* __restrict__ gfeat, int c0)
{
    int g = blockIdx.x;
    int cl = blockIdx.y * 64 + threadIdx.x;
    if (cl >= CCH) return;
    int s = gstart[g], e = gstart[g + 1];
    float mx = 0.f, sum = 0.f;  // post-relu values >= 0
    for (int n = s; n < e; n++) {
        float v = hh[(size_t)n * CCH + cl];
        mx = fmaxf(mx, v);
        sum += v;
    }
    float cnt = (float)(e - s);
    gfeat[g * 1560 + c0 + cl] = mx;
    gfeat[g * 1560 + 780 + c0 + cl] = sum / fmaxf(cnt, 1.f);
}

// ---------------------------------------------------------------------------
// Protein branch 2: M[b,t,o,k] = sum_{c: t2[b,c]==t} Wc2[o,c,k]
// ---------------------------------------------------------------------------
__global__ void k_build_M(const int* __restrict__ t2, const float* __restrict__ Wc2,
                          float* __restrict__ Mbuf)
{
    __shared__ float Ml[26 * 256];
    int b = blockIdx.x, t = threadIdx.x;
    for (int j = t; j < 26 * 256; j += 256) Ml[j] = 0.f;
    __syncthreads();
    int o = t >> 3, k = t & 7;
    const int* tb = t2 + b * 1000;
    for (int cc = 0; cc < 1000; cc++) {
        int tok = tb[cc];
        Ml[tok * 256 + t] += Wc2[o * 8000 + cc * 8 + k];
    }
    __syncthreads();
    float* Mb = Mbuf + (size_t)b * (26 * 256);
    for (int j = t; j < 26 * 256; j += 256) Mb[j] = Ml[j];
}

// out[b,o,l] = bc2[o] + sum_t sum_k M[b,t,o,k]*emb[t,l+k]
__global__ void k_conv2(const float* __restrict__ Mbuf, const float* __restrict__ emb,
                        const float* __restrict__ bc2, float* __restrict__ xt2c)
{
    int idx = blockIdx.x * blockDim.x + threadIdx.x;
    if (idx >= G * 3872) return;
    int b = idx / 3872, r = idx % 3872;
    int o = r / 121, l = r % 121;
    const float* Mb = Mbuf + (size_t)b * (26 * 256);
    float acc = bc2[o];
    for (int t = 0; t < 26; t++) {
        const float* mrow = Mb + t * 256 + o * 8;
        const float* erow = emb + t * 128 + l;
#pragma unroll
        for (int k = 0; k < 8; k++) acc += mrow[k] * erow[k];
    }
    xt2c[idx] = acc;
}

// Protein branch 1: direct small conv1d. out [B,32,17]
__global__ void k_conv1(const float* __restrict__ t1, const float* __restrict__ Wc1,
                        const float* __restrict__ bc1, float* __restrict__ xt1c)
{
    int idx = blockIdx.x * blockDim.x + threadIdx.x;
    if (idx >= G * 544) return;
    int b = idx / 544, r = idx % 544;
    int o = r / 17, l = r % 17;
    float acc = bc1[o];
    const float* xb = t1 + b * 480;   // [20,24]
    const float* wo = Wc1 + o * 160;  // [20,8]
    for (int cc = 0; cc < 20; cc++) {
        const float* xr = xb + cc * 24 + l;
        const float* wr = wo + cc * 8;
#pragma unroll
        for (int k = 0; k < 8; k++) acc += xr[k] * wr[k];
    }
    xt1c[idx] = acc;
}

// ---------------------------------------------------------------------------
extern "C" void kernel_launch(void* const* d_in, const int* in_sizes, int n_in,
                              void* d_out, int out_size, void* d_ws, size_t ws_size,
                              hipStream_t stream)
{
    const float* x       = (const float*)d_in[0];
    const int*   ei      = (const int*)  d_in[1];
    const int*   batch   = (const int*)  d_in[2];
    const float* t1      = (const float*)d_in[3];
    const int*   t2      = (const int*)  d_in[4];
    const float* W_gat   = (const float*)d_in[5];
    const float* att_src = (const float*)d_in[6];
    const float* att_dst = (const float*)d_in[7];
    const float* b_gat   = (const float*)d_in[8];
    const float* W_gcn   = (const float*)d_in[9];
    const float* b_gcn   = (const float*)d_in[10];
    const float* W_fcg1  = (const float*)d_in[11];
    const float* b_fcg1  = (const float*)d_in[12];
    const float* W_fcg2  = (const float*)d_in[13];
    const float* b_fcg2  = (const float*)d_in[14];
    const float* emb     = (const float*)d_in[15];
    const float* Wc2     = (const float*)d_in[16];
    const float* bc2     = (const float*)d_in[17];
    const float* W_fc2xt = (const float*)d_in[18];
    const float* b_fc2xt = (const float*)d_in[19];
    const float* Wc1     = (const float*)d_in[20];
    const float* bc1     = (const float*)d_in[21];
    const float* W_fc1xt = (const float*)d_in[22];
    const float* b_fc1xt = (const float*)d_in[23];
    const float* W_fc1   = (const float*)d_in[24];
    const float* b_fc1   = (const float*)d_in[25];
    const float* W_fc2   = (const float*)d_in[26];
    const float* b_fc2   = (const float*)d_in[27];
    const float* W_out   = (const float*)d_in[28];
    const float* b_out   = (const float*)d_in[29];

    char* wsb = (char*)d_ws;
    size_t off = 0;
    auto alloc = [&](size_t bytes) -> char* {
        char* p = wsb + off;
        off += (bytes + 255) & ~(size_t)255;
        return p;
    };

    float* gat_out = (float*)alloc((size_t)N * C * 4);    // 156 MB, persistent
    float* chunk_a = (float*)alloc((size_t)N * CCH * 4);  // h1 chunk, then h2 chunk
    float* chunk_b = (float*)alloc((size_t)N * CCH * 4);  // gcn-out chunk
    float* V_s    = (float*)alloc((size_t)F * H * 4);
    float* V_d    = (float*)alloc((size_t)F * H * 4);
    float* a_s    = (float*)alloc((size_t)N * H * 4);
    float* a_d    = (float*)alloc((size_t)N * H * 4);
    float* m_ns   = (float*)alloc((size_t)N * H * 4);
    float* s_ns   = (float*)alloc((size_t)N * H * 4);
    float* alpha  = (float*)alloc((size_t)NE * H * 4);
    float* dinv   = (float*)alloc((size_t)N * 4);
    float* gfeat  = (float*)alloc((size_t)G * 1560 * 4);
    float* g1     = (float*)alloc((size_t)G * 1500 * 4);
    float* Mbuf   = (float*)alloc((size_t)G * 26 * 256 * 4);
    float* xt2c   = (float*)alloc((size_t)G * 3872 * 4);
    float* xt1c   = (float*)alloc((size_t)G * 544 * 4);
    float* xc     = (float*)alloc((size_t)G * 384 * 4);
    float* f1     = (float*)alloc((size_t)G * 1024 * 4);
    float* f2     = (float*)alloc((size_t)G * 512 * 4);
    int* deg       = (int*)alloc((size_t)N * 4);
    int* row_start = (int*)alloc((size_t)(N + 1) * 4);
    int* fill_cnt  = (int*)alloc((size_t)N * 4);
    int* edge_list = (int*)alloc((size_t)NE * 4);
    int* gcnt      = (int*)alloc((size_t)G * 4);
    int* gstart    = (int*)alloc((size_t)(G + 1) * 4);

    if (off > ws_size) {
        fprintf(stderr, "kernel_launch: workspace too small: need %zu have %zu\n", off, ws_size);
        return;
    }

    hipMemsetAsync(deg, 0, (size_t)N * 4, stream);
    hipMemsetAsync(fill_cnt, 0, (size_t)N * 4, stream);
    hipMemsetAsync(gcnt, 0, (size_t)G * 4, stream);

    dim3 gblock(16, 16);

    // ---- attention logits (no h1 needed) ----
    k_Vsd<<<CDIV(F * H, 256), 256, 0, stream>>>(W_gat, att_src, att_dst, V_s, V_d);
    k_ascores<<<CDIV(N, 256), 256, 0, stream>>>(x, V_s, V_d, a_s, a_d);

    // ---- CSR + graph ranges ----
    count_deg<<<CDIV(NE, 256), 256, 0, stream>>>(ei, deg);
    scan_int<<<1, 1024, 0, stream>>>(deg, row_start, N);
    fill_csr<<<CDIV(NE, 256), 256, 0, stream>>>(ei, row_start, fill_cnt, edge_list);
    k_graph_cnt<<<CDIV(N, 256), 256, 0, stream>>>(batch, gcnt);
    scan_int<<<1, 1024, 0, stream>>>(gcnt, gstart, G);

    // ---- softmax ----
    k_softmax_stats<<<CDIV(N * H, 256), 256, 0, stream>>>(ei, row_start, edge_list, a_s, a_d, m_ns, s_ns);
    k_alpha<<<CDIV(NE * H, 256), 256, 0, stream>>>(ei, a_s, a_d, m_ns, s_ns, alpha);

    // ---- GAT: 5 chunks of 2 heads (156 cols) ----
    for (int c0 = 0; c0 < C; c0 += CCH) {
        dim3 grid(CDIV(N, 64), CDIV(CCH, 64));
        gemm_tiled<<<grid, gblock, 0, stream>>>(x, W_gat + c0, nullptr, chunk_a,
                                                N, CCH, F, F, C, CCH, 0);
        gat_agg_chunk<<<N, 192, 0, stream>>>(chunk_a, alpha, ei, row_start, edge_list,
                                             b_gat, gat_out, c0);
    }

    // ---- GCN: 5 column chunks, fused agg + pool ----
    k_dinv<<<CDIV(N, 256), 256, 0, stream>>>(deg, dinv);
    for (int c0 = 0; c0 < C; c0 += CCH) {
        dim3 grid(CDIV(N, 64), CDIV(CCH, 64));
        gemm_tiled<<<grid, gblock, 0, stream>>>(gat_out, W_gcn + c0, nullptr, chunk_a,
                                                N, CCH, C, C, C, CCH, 0);
        gcn_agg_chunk<<<N, 192, 0, stream>>>(chunk_a, dinv, ei, row_start, edge_list,
                                             b_gcn, chunk_b, c0);
        dim3 pgrid(G, CDIV(CCH, 64));
        k_pool_chunk<<<pgrid, 64, 0, stream>>>(chunk_b, gstart, gfeat, c0);
    }

    // ---- graph FC branch ----
    {
        dim3 grid(CDIV(G, 64), CDIV(1500, 64));
        gemm_tiled<<<grid, gblock, 0, stream>>>(gfeat, W_fcg1, b_fcg1, g1,
                                                G, 1500, 1560, 1560, 1500, 1500, 1);
    }
    {
        dim3 grid(CDIV(G, 64), CDIV(128, 64));
        gemm_tiled<<<grid, gblock, 0, stream>>>(g1, W_fcg2, b_fcg2, xc,
                                                G, 128, 1500, 1500, 128, 384, 0);
    }

    // ---- protein branch 2 ----
    k_build_M<<<G, 256, 0, stream>>>(t2, Wc2, Mbuf);
    k_conv2<<<CDIV(G * 3872, 256), 256, 0, stream>>>(Mbuf, emb, bc2, xt2c);
    {
        dim3 grid(CDIV(G, 64), CDIV(128, 64));
        gemm_tiled<<<grid, gblock, 0, stream>>>(xt2c, W_fc2xt, b_fc2xt, xc + 256,
                                                G, 128, 3872, 3872, 128, 384, 0);
    }

    // ---- protein branch 1 ----
    k_conv1<<<CDIV(G * 544, 256), 256, 0, stream>>>(t1, Wc1, bc1, xt1c);
    {
        dim3 grid(CDIV(G, 64), CDIV(128, 64));
        gemm_tiled<<<grid, gblock, 0, stream>>>(xt1c, W_fc1xt, b_fc1xt, xc + 128,
                                                G, 128, 544, 544, 128, 384, 0);
    }

    // ---- head ----
    {
        dim3 grid(CDIV(G, 64), CDIV(1024, 64));
        gemm_tiled<<<grid, gblock, 0, stream>>>(xc, W_fc1, b_fc1, f1,
                                                G, 1024, 384, 384, 1024, 1024, 1);
    }
    {
        dim3 grid(CDIV(G, 64), CDIV(512, 64));
        gemm_tiled<<<grid, gblock, 0, stream>>>(f1, W_fc2, b_fc2, f2,
                                                G, 512, 1024, 1024, 512, 512, 1);
    }
    {
        dim3 grid(CDIV(G, 64), 1);
        gemm_tiled<<<grid, gblock, 0, stream>>>(f2, W_out, b_out, (float*)d_out,
                                                G, 1, 512, 512, 1, 1, 0);
    }
}

// Round 3
// 3010.611 us; speedup vs baseline: 1.8532x; 1.8532x over previous
//
#include <hip/hip_runtime.h>
#include <cstdio>
#include <cstdint>

#define CDIV(a,b) (((a)+(b)-1)/(b))

static const int N   = 50000;   // nodes
static const int NE0 = 150000;  // edges w/o self loops
static const int NE  = 200000;  // edges with self loops
static const int H   = 10;      // heads
static const int F   = 78;      // per-head features
static const int C   = 780;     // H*F
static const int G   = 128;     // graphs
static const int KP_GAT = 96;   // 78 padded to 3*32
static const int KP_GCN = 800;  // 780 padded to 25*32

typedef __attribute__((ext_vector_type(8))) short bf16x8;
typedef __attribute__((ext_vector_type(4))) float f32x4;
typedef __attribute__((ext_vector_type(8))) unsigned short us8;

__device__ __forceinline__ float bf2f(unsigned short u) {
    return __uint_as_float(((unsigned int)u) << 16);
}
__device__ __forceinline__ unsigned short f2bf(float f) {
    unsigned int u = __float_as_uint(f);
    u = (u + 0x7fff + ((u >> 16) & 1)) >> 16;   // RNE
    return (unsigned short)u;
}

// ---------------------------------------------------------------------------
// bf16 MFMA GEMM: C[M,Nn] = A[M,K] @ B[K,Nn], A bf16 [M][lda] (lda=Kpad),
// Bt bf16 [Nn][ldb] (B transposed, ldb=Kpad), out bf16 [M][ldc].
// Block 256 thr = 4 waves (2x2), tile 128x128, BK=32, 16 MFMA/wave/K-step.
// lda/ldb must be multiples of 8 (16B-aligned rows); K fully padded with 0s.
// ---------------------------------------------------------------------------
__global__ __launch_bounds__(256)
void gemm_mfma(const unsigned short* __restrict__ A,
               const unsigned short* __restrict__ Bt,
               unsigned short* __restrict__ Cb,
               int M, int Nn, int kSteps, int lda, int ldb, int ldc)
{
    __shared__ unsigned short As[128][40];   // +8 pad: 2-way bank pattern (free)
    __shared__ unsigned short Bs[128][40];
    const int tid = threadIdx.x;
    const int lane = tid & 63;
    const int wave = tid >> 6;
    const int wm = (wave >> 1) * 64, wn = (wave & 1) * 64;
    const int bm = blockIdx.x * 128, bn = blockIdx.y * 128;

    f32x4 acc[4][4] = {};

    const int lrow = tid >> 2;        // 0..63
    const int lk   = (tid & 3) * 8;   // 0,8,16,24
    const int mrow = lane & 15, quad = lane >> 4;

    for (int ks = 0; ks < kSteps; ks++) {
        const int k0 = ks * 32;
        {   // stage A rows (clamped; garbage rows discarded by store guard)
            int r0 = min(bm + lrow, M - 1);
            int r1 = min(bm + lrow + 64, M - 1);
            *(us8*)&As[lrow][lk]      = *(const us8*)&A[(size_t)r0 * lda + k0 + lk];
            *(us8*)&As[lrow + 64][lk] = *(const us8*)&A[(size_t)r1 * lda + k0 + lk];
            int n0 = min(bn + lrow, Nn - 1);
            int n1 = min(bn + lrow + 64, Nn - 1);
            *(us8*)&Bs[lrow][lk]      = *(const us8*)&Bt[(size_t)n0 * ldb + k0 + lk];
            *(us8*)&Bs[lrow + 64][lk] = *(const us8*)&Bt[(size_t)n1 * ldb + k0 + lk];
        }
        __syncthreads();
        bf16x8 af[4], bfr[4];
#pragma unroll
        for (int i = 0; i < 4; i++) {
            af[i]  = *(const bf16x8*)&As[wm + i * 16 + mrow][quad * 8];
            bfr[i] = *(const bf16x8*)&Bs[wn + i * 16 + mrow][quad * 8];
        }
#pragma unroll
        for (int i = 0; i < 4; i++)
#pragma unroll
            for (int j = 0; j < 4; j++)
                acc[i][j] = __builtin_amdgcn_mfma_f32_16x16x32_bf16(af[i], bfr[j], acc[i][j], 0, 0, 0);
        __syncthreads();
    }

    // epilogue: C/D layout col=lane&15, row=quad*4+reg  [m89-verified]
#pragma unroll
    for (int i = 0; i < 4; i++) {
#pragma unroll
        for (int j = 0; j < 4; j++) {
            int col = bn + wn + j * 16 + mrow;
            if (col >= Nn) continue;
#pragma unroll
            for (int r = 0; r < 4; r++) {
                int row = bm + wm + i * 16 + quad * 4 + r;
                if (row >= M) continue;
                Cb[(size_t)row * ldc + col] = f2bf(acc[i][j][r]);
            }
        }
    }
}

// ---------------------------------------------------------------------------
// casts
// ---------------------------------------------------------------------------
__global__ void k_cast_pad_x(const float* __restrict__ x, unsigned short* __restrict__ xb)
{
    int idx = blockIdx.x * blockDim.x + threadIdx.x;
    if (idx >= N * KP_GAT) return;
    int n = idx / KP_GAT, k = idx % KP_GAT;
    float v = (k < F) ? x[(size_t)n * F + k] : 0.f;
    xb[idx] = f2bf(v);
}

// W[K][Nn] row-major fp32 -> Wt[Nn][Kpad] bf16 (transpose + zero-pad)
__global__ void k_transpose_cast(const float* __restrict__ W, unsigned short* __restrict__ Wt,
                                 int K, int Nn, int Kpad)
{
    int idx = blockIdx.x * blockDim.x + threadIdx.x;
    if (idx >= Nn * Kpad) return;
    int n = idx / Kpad, k = idx % Kpad;
    float v = (k < K) ? W[(size_t)k * Nn + n] : 0.f;
    Wt[idx] = f2bf(v);
}

// ---------------------------------------------------------------------------
// V_s[k,h] = sum_f W_gat[k, h*F+f] * att_src[h,f]  (78x10), same for V_d.
// ---------------------------------------------------------------------------
__global__ void k_Vsd(const float* __restrict__ W_gat, const float* __restrict__ att_src,
                      const float* __restrict__ att_dst, float* __restrict__ V_s,
                      float* __restrict__ V_d)
{
    int idx = blockIdx.x * blockDim.x + threadIdx.x;
    if (idx >= F * H) return;
    int k = idx / H, h = idx % H;
    const float* wr = W_gat + (size_t)k * C + h * F;
    const float* as = att_src + h * F;
    const float* ad = att_dst + h * F;
    float s = 0.f, d = 0.f;
    for (int f = 0; f < F; f++) { float w = wr[f]; s += w * as[f]; d += w * ad[f]; }
    V_s[idx] = s; V_d[idx] = d;
}

__global__ void k_ascores(const float* __restrict__ x, const float* __restrict__ V_s,
                          const float* __restrict__ V_d, float* __restrict__ a_s,
                          float* __restrict__ a_d)
{
    __shared__ float Vs[F * H], Vd[F * H];
    int t = threadIdx.x;
    for (int i = t; i < F * H; i += 256) { Vs[i] = V_s[i]; Vd[i] = V_d[i]; }
    __syncthreads();
    int n = blockIdx.x * 256 + t;
    if (n >= N) return;
    const float* xr = x + (size_t)n * F;
    float accs[H] = {}, accd[H] = {};
    for (int k = 0; k < F; k++) {
        float xv = xr[k];
        const float* vs = &Vs[k * H];
        const float* vd = &Vd[k * H];
#pragma unroll
        for (int h = 0; h < H; h++) { accs[h] += xv * vs[h]; accd[h] += xv * vd[h]; }
    }
    for (int h = 0; h < H; h++) { a_s[n * H + h] = accs[h]; a_d[n * H + h] = accd[h]; }
}

// ---------------------------------------------------------------------------
// CSR build
// ---------------------------------------------------------------------------
__global__ void count_deg(const int* __restrict__ ei, int* __restrict__ deg)
{
    int e = blockIdx.x * blockDim.x + threadIdx.x;
    if (e >= NE) return;
    int d = (e < NE0) ? ei[NE0 + e] : (e - NE0);
    atomicAdd(&deg[d], 1);
}

__global__ void scan_int(const int* __restrict__ cnt, int* __restrict__ row_start, int n)
{
    __shared__ int partial[1024];
    int tid = threadIdx.x;
    int per = CDIV(n, 1024);
    int start = tid * per, end = min(start + per, n);
    int sum = 0;
    for (int i = start; i < end; i++) sum += cnt[i];
    partial[tid] = sum;
    __syncthreads();
    for (int off = 1; off < 1024; off *= 2) {
        int v = (tid >= off) ? partial[tid - off] : 0;
        __syncthreads();
        partial[tid] += v;
        __syncthreads();
    }
    int base = (tid > 0) ? partial[tid - 1] : 0;
    for (int i = start; i < end; i++) { row_start[i] = base; base += cnt[i]; }
    if (tid == 1023) row_start[n] = base;
}

__global__ void fill_csr(const int* __restrict__ ei, const int* __restrict__ row_start,
                         int* __restrict__ fill_cnt, int* __restrict__ edge_list)
{
    int e = blockIdx.x * blockDim.x + threadIdx.x;
    if (e >= NE) return;
    int d = (e < NE0) ? ei[NE0 + e] : (e - NE0);
    int pos = row_start[d] + atomicAdd(&fill_cnt[d], 1);
    edge_list[pos] = e;
}

__global__ void k_graph_cnt(const int* __restrict__ batch, int* __restrict__ gcnt)
{
    int n = blockIdx.x * blockDim.x + threadIdx.x;
    if (n >= N) return;
    atomicAdd(&gcnt[batch[n]], 1);
}

// ---------------------------------------------------------------------------
// GAT softmax
// ---------------------------------------------------------------------------
__global__ void k_softmax_stats(const int* __restrict__ ei, const int* __restrict__ row_start,
                                const int* __restrict__ edge_list,
                                const float* __restrict__ a_s, const float* __restrict__ a_d,
                                float* __restrict__ m_ns, float* __restrict__ s_ns)
{
    int idx = blockIdx.x * blockDim.x + threadIdx.x;
    if (idx >= N * H) return;
    int n = idx / H, h = idx % H;
    float ad = a_d[idx];
    int rs = row_start[n], re = row_start[n + 1];
    float m = -INFINITY, s = 0.f;
    for (int i = rs; i < re; i++) {
        int e = edge_list[i];
        int sr = (e < NE0) ? ei[e] : (e - NE0);
        float ev = a_s[sr * H + h] + ad;
        ev = (ev > 0.f) ? ev : 0.2f * ev;
        if (ev <= m) {
            s += expf(ev - m);
        } else {
            s = s * expf(m - ev) + 1.f;
            m = ev;
        }
    }
    m_ns[idx] = m;
    s_ns[idx] = s;
}

__global__ void k_alpha(const int* __restrict__ ei, const float* __restrict__ a_s,
                        const float* __restrict__ a_d, const float* __restrict__ m_ns,
                        const float* __restrict__ s_ns, float* __restrict__ alpha)
{
    int idx = blockIdx.x * blockDim.x + threadIdx.x;
    if (idx >= NE * H) return;
    int e = idx / H, h = idx % H;
    int sr = (e < NE0) ? ei[e] : (e - NE0);
    int ds = (e < NE0) ? ei[NE0 + e] : (e - NE0);
    float ev = a_s[sr * H + h] + a_d[ds * H + h];
    ev = (ev > 0.f) ? ev : 0.2f * ev;
    alpha[idx] = expf(ev - m_ns[ds * H + h]) / (s_ns[ds * H + h] + 1e-16f);
}

// ---------------------------------------------------------------------------
// GAT aggregation, full width: h1 bf16 [N][780] -> gat_out bf16 [N][800] (padded)
// ---------------------------------------------------------------------------
__global__ void gat_agg_full(const unsigned short* __restrict__ h1, const float* __restrict__ alpha,
                             const int* __restrict__ ei, const int* __restrict__ row_start,
                             const int* __restrict__ edge_list, const float* __restrict__ b_gat,
                             unsigned short* __restrict__ out)
{
    int n = blockIdx.x;
    int rs = row_start[n], re = row_start[n + 1];
    for (int c = threadIdx.x; c < KP_GCN; c += 256) {
        float r = 0.f;
        if (c < C) {
            int h = c / F;
            float acc = 0.f;
            for (int i = rs; i < re; i++) {
                int e = edge_list[i];
                int sr = (e < NE0) ? ei[e] : (e - NE0);
                acc += alpha[e * H + h] * bf2f(h1[(size_t)sr * C + c]);
            }
            r = fmaxf(acc + b_gat[c], 0.f);
        }
        out[(size_t)n * KP_GCN + c] = f2bf(r);
    }
}

__global__ void k_dinv(const int* __restrict__ deg, float* __restrict__ dinv)
{
    int n = blockIdx.x * blockDim.x + threadIdx.x;
    if (n >= N) return;
    int d = deg[n];
    dinv[n] = (d > 0) ? 1.f / sqrtf((float)d) : 0.f;
}

// h2 bf16 [N][780] gathered -> gcn_out bf16 [N][780]
__global__ void gcn_agg_full(const unsigned short* __restrict__ h2, const float* __restrict__ dinv,
                             const int* __restrict__ ei, const int* __restrict__ row_start,
                             const int* __restrict__ edge_list, const float* __restrict__ b_gcn,
                             unsigned short* __restrict__ out)
{
    int n = blockIdx.x;
    float dn = dinv[n];
    int rs = row_start[n], re = row_start[n + 1];
    for (int c = threadIdx.x; c < C; c += 256) {
        float acc = 0.f;
        for (int i = rs; i < re; i++) {
            int e = edge_list[i];
            int sr = (e < NE0) ? ei[e] : (e - NE0);
            acc += dinv[sr] * bf2f(h2[(size_t)sr * C + c]);
        }
        out[(size_t)n * C + c] = f2bf(fmaxf(acc * dn + b_gcn[c], 0.f));
    }
}

// max+mean pool from bf16 [N][780]
__global__ void k_pool_full(const unsigned short* __restrict__ hh, const int* __restrict__ gstart,
                            float* __restrict__ gfeat)
{
    int g = blockIdx.x;
    int c = blockIdx.y * 64 + threadIdx.x;
    if (c >= C) return;
    int s = gstart[g], e = gstart[g + 1];
    float mx = 0.f, sum = 0.f;   // post-relu values >= 0
    for (int n = s; n < e; n++) {
        float v = bf2f(hh[(size_t)n * C + c]);
        mx = fmaxf(mx, v);
        sum += v;
    }
    float cnt = (float)(e - s);
    gfeat[g * 1560 + c] = mx;
    gfeat[g * 1560 + 780 + c] = sum / fmaxf(cnt, 1.f);
}

// ---------------------------------------------------------------------------
// fp32 tiled GEMM (FC/head branches)
// ---------------------------------------------------------------------------
__global__ void gemm_tiled(const float* __restrict__ A, const float* __restrict__ B,
                           const float* __restrict__ bias, float* __restrict__ Cc,
                           int M, int Nn, int K, int lda, int ldb, int ldc, int relu)
{
    __shared__ float As[16][68];
    __shared__ float Bs[16][68];
    const int tx = threadIdx.x, ty = threadIdx.y;
    const int tid = ty * 16 + tx;
    const int bm = blockIdx.x * 64, bn = blockIdx.y * 64;

    float acc[4][4] = {};

    for (int k0 = 0; k0 < K; k0 += 16) {
        for (int i = tid; i < 64 * 16; i += 256) {
            int m = i >> 4, kk = i & 15;
            int gm = bm + m, gk = k0 + kk;
            As[kk][m] = (gm < M && gk < K) ? A[(size_t)gm * lda + gk] : 0.f;
        }
        for (int i = tid; i < 16 * 64; i += 256) {
            int kk = i >> 6, n = i & 63;
            int gk = k0 + kk, gn = bn + n;
            Bs[kk][n] = (gk < K && gn < Nn) ? B[(size_t)gk * ldb + gn] : 0.f;
        }
        __syncthreads();
#pragma unroll
        for (int kk = 0; kk < 16; kk++) {
            float4 a4 = *(const float4*)&As[kk][ty * 4];
            float4 b4 = *(const float4*)&Bs[kk][tx * 4];
            float a[4] = {a4.x, a4.y, a4.z, a4.w};
            float b[4] = {b4.x, b4.y, b4.z, b4.w};
#pragma unroll
            for (int i = 0; i < 4; i++)
#pragma unroll
                for (int j = 0; j < 4; j++)
                    acc[i][j] += a[i] * b[j];
        }
        __syncthreads();
    }

    for (int i = 0; i < 4; i++) {
        int gm = bm + ty * 4 + i;
        if (gm >= M) continue;
        for (int j = 0; j < 4; j++) {
            int gn = bn + tx * 4 + j;
            if (gn >= Nn) continue;
            float v = acc[i][j];
            if (bias) v += bias[gn];
            if (relu) v = fmaxf(v, 0.f);
            Cc[(size_t)gm * ldc + gn] = v;
        }
    }
}

// ---------------------------------------------------------------------------
// protein branches
// ---------------------------------------------------------------------------
__global__ void k_build_M(const int* __restrict__ t2, const float* __restrict__ Wc2,
                          float* __restrict__ Mbuf)
{
    __shared__ float Ml[26 * 256];
    int b = blockIdx.x, t = threadIdx.x;
    for (int j = t; j < 26 * 256; j += 256) Ml[j] = 0.f;
    __syncthreads();
    int o = t >> 3, k = t & 7;
    const int* tb = t2 + b * 1000;
    for (int cc = 0; cc < 1000; cc++) {
        int tok = tb[cc];
        Ml[tok * 256 + t] += Wc2[o * 8000 + cc * 8 + k];
    }
    __syncthreads();
    float* Mb = Mbuf + (size_t)b * (26 * 256);
    for (int j = t; j < 26 * 256; j += 256) Mb[j] = Ml[j];
}

__global__ void k_conv2(const float* __restrict__ Mbuf, const float* __restrict__ emb,
                        const float* __restrict__ bc2, float* __restrict__ xt2c)
{
    int idx = blockIdx.x * blockDim.x + threadIdx.x;
    if (idx >= G * 3872) return;
    int b = idx / 3872, r = idx % 3872;
    int o = r / 121, l = r % 121;
    const float* Mb = Mbuf + (size_t)b * (26 * 256);
    float acc = bc2[o];
    for (int t = 0; t < 26; t++) {
        const float* mrow = Mb + t * 256 + o * 8;
        const float* erow = emb + t * 128 + l;
#pragma unroll
        for (int k = 0; k < 8; k++) acc += mrow[k] * erow[k];
    }
    xt2c[idx] = acc;
}

__global__ void k_conv1(const float* __restrict__ t1, const float* __restrict__ Wc1,
                        const float* __restrict__ bc1, float* __restrict__ xt1c)
{
    int idx = blockIdx.x * blockDim.x + threadIdx.x;
    if (idx >= G * 544) return;
    int b = idx / 544, r = idx % 544;
    int o = r / 17, l = r % 17;
    float acc = bc1[o];
    const float* xb = t1 + b * 480;
    const float* wo = Wc1 + o * 160;
    for (int cc = 0; cc < 20; cc++) {
        const float* xr = xb + cc * 24 + l;
        const float* wr = wo + cc * 8;
#pragma unroll
        for (int k = 0; k < 8; k++) acc += xr[k] * wr[k];
    }
    xt1c[idx] = acc;
}

// ---------------------------------------------------------------------------
extern "C" void kernel_launch(void* const* d_in, const int* in_sizes, int n_in,
                              void* d_out, int out_size, void* d_ws, size_t ws_size,
                              hipStream_t stream)
{
    const float* x       = (const float*)d_in[0];
    const int*   ei      = (const int*)  d_in[1];
    const int*   batch   = (const int*)  d_in[2];
    const float* t1      = (const float*)d_in[3];
    const int*   t2      = (const int*)  d_in[4];
    const float* W_gat   = (const float*)d_in[5];
    const float* att_src = (const float*)d_in[6];
    const float* att_dst = (const float*)d_in[7];
    const float* b_gat   = (const float*)d_in[8];
    const float* W_gcn   = (const float*)d_in[9];
    const float* b_gcn   = (const float*)d_in[10];
    const float* W_fcg1  = (const float*)d_in[11];
    const float* b_fcg1  = (const float*)d_in[12];
    const float* W_fcg2  = (const float*)d_in[13];
    const float* b_fcg2  = (const float*)d_in[14];
    const float* emb     = (const float*)d_in[15];
    const float* Wc2     = (const float*)d_in[16];
    const float* bc2     = (const float*)d_in[17];
    const float* W_fc2xt = (const float*)d_in[18];
    const float* b_fc2xt = (const float*)d_in[19];
    const float* Wc1     = (const float*)d_in[20];
    const float* bc1     = (const float*)d_in[21];
    const float* W_fc1xt = (const float*)d_in[22];
    const float* b_fc1xt = (const float*)d_in[23];
    const float* W_fc1   = (const float*)d_in[24];
    const float* b_fc1   = (const float*)d_in[25];
    const float* W_fc2   = (const float*)d_in[26];
    const float* b_fc2   = (const float*)d_in[27];
    const float* W_out   = (const float*)d_in[28];
    const float* b_out   = (const float*)d_in[29];

    char* wsb = (char*)d_ws;
    size_t off = 0;
    auto alloc = [&](size_t bytes) -> char* {
        char* p = wsb + off;
        off += (bytes + 255) & ~(size_t)255;
        return p;
    };

    unsigned short* h_buf   = (unsigned short*)alloc((size_t)N * C * 2);       // h1 then h2 (78 MB)
    unsigned short* gat_out = (unsigned short*)alloc((size_t)N * KP_GCN * 2);  // 80 MB; reused as gcn_out
    unsigned short* xb      = (unsigned short*)alloc((size_t)N * KP_GAT * 2);  // 9.6 MB
    unsigned short* Wgat_t  = (unsigned short*)alloc((size_t)C * KP_GAT * 2);
    unsigned short* Wgcn_t  = (unsigned short*)alloc((size_t)C * KP_GCN * 2);
    float* V_s    = (float*)alloc((size_t)F * H * 4);
    float* V_d    = (float*)alloc((size_t)F * H * 4);
    float* a_s    = (float*)alloc((size_t)N * H * 4);
    float* a_d    = (float*)alloc((size_t)N * H * 4);
    float* m_ns   = (float*)alloc((size_t)N * H * 4);
    float* s_ns   = (float*)alloc((size_t)N * H * 4);
    float* alpha  = (float*)alloc((size_t)NE * H * 4);
    float* dinv   = (float*)alloc((size_t)N * 4);
    float* gfeat  = (float*)alloc((size_t)G * 1560 * 4);
    float* g1     = (float*)alloc((size_t)G * 1500 * 4);
    float* Mbuf   = (float*)alloc((size_t)G * 26 * 256 * 4);
    float* xt2c   = (float*)alloc((size_t)G * 3872 * 4);
    float* xt1c   = (float*)alloc((size_t)G * 544 * 4);
    float* xc     = (float*)alloc((size_t)G * 384 * 4);
    float* f1     = (float*)alloc((size_t)G * 1024 * 4);
    float* f2     = (float*)alloc((size_t)G * 512 * 4);
    int* deg       = (int*)alloc((size_t)N * 4);
    int* row_start = (int*)alloc((size_t)(N + 1) * 4);
    int* fill_cnt  = (int*)alloc((size_t)N * 4);
    int* edge_list = (int*)alloc((size_t)NE * 4);
    int* gcnt      = (int*)alloc((size_t)G * 4);
    int* gstart    = (int*)alloc((size_t)(G + 1) * 4);

    if (off > ws_size) {
        fprintf(stderr, "kernel_launch: workspace too small: need %zu have %zu\n", off, ws_size);
        return;
    }

    hipMemsetAsync(deg, 0, (size_t)N * 4, stream);
    hipMemsetAsync(fill_cnt, 0, (size_t)N * 4, stream);
    hipMemsetAsync(gcnt, 0, (size_t)G * 4, stream);

    dim3 gblock(16, 16);

    // ---- casts (independent of everything else) ----
    k_cast_pad_x<<<CDIV(N * KP_GAT, 256), 256, 0, stream>>>(x, xb);
    k_transpose_cast<<<CDIV(C * KP_GAT, 256), 256, 0, stream>>>(W_gat, Wgat_t, F, C, KP_GAT);
    k_transpose_cast<<<CDIV(C * KP_GCN, 256), 256, 0, stream>>>(W_gcn, Wgcn_t, C, C, KP_GCN);

    // ---- attention logits (fp32, no h1 needed) ----
    k_Vsd<<<CDIV(F * H, 256), 256, 0, stream>>>(W_gat, att_src, att_dst, V_s, V_d);
    k_ascores<<<CDIV(N, 256), 256, 0, stream>>>(x, V_s, V_d, a_s, a_d);

    // ---- CSR + graph ranges ----
    count_deg<<<CDIV(NE, 256), 256, 0, stream>>>(ei, deg);
    scan_int<<<1, 1024, 0, stream>>>(deg, row_start, N);
    fill_csr<<<CDIV(NE, 256), 256, 0, stream>>>(ei, row_start, fill_cnt, edge_list);
    k_graph_cnt<<<CDIV(N, 256), 256, 0, stream>>>(batch, gcnt);
    scan_int<<<1, 1024, 0, stream>>>(gcnt, gstart, G);

    // ---- softmax ----
    k_softmax_stats<<<CDIV(N * H, 256), 256, 0, stream>>>(ei, row_start, edge_list, a_s, a_d, m_ns, s_ns);
    k_alpha<<<CDIV(NE * H, 256), 256, 0, stream>>>(ei, a_s, a_d, m_ns, s_ns, alpha);
    k_dinv<<<CDIV(N, 256), 256, 0, stream>>>(deg, dinv);

    // ---- GAT: h1 = x @ W_gat (bf16 MFMA), then aggregate ----
    {
        dim3 grid(CDIV(N, 128), CDIV(C, 128));
        gemm_mfma<<<grid, 256, 0, stream>>>(xb, Wgat_t, h_buf, N, C, KP_GAT / 32, KP_GAT, KP_GAT, C);
    }
    gat_agg_full<<<N, 256, 0, stream>>>(h_buf, alpha, ei, row_start, edge_list, b_gat, gat_out);

    // ---- GCN: h2 = gat_out @ W_gcn (bf16 MFMA), aggregate, pool ----
    {
        dim3 grid(CDIV(N, 128), CDIV(C, 128));
        gemm_mfma<<<grid, 256, 0, stream>>>(gat_out, Wgcn_t, h_buf, N, C, KP_GCN / 32, KP_GCN, KP_GCN, C);
    }
    // gcn_out reuses gat_out's buffer (dead after GEMM), stride C
    unsigned short* gcn_out = gat_out;
    gcn_agg_full<<<N, 256, 0, stream>>>(h_buf, dinv, ei, row_start, edge_list, b_gcn, gcn_out);
    {
        dim3 pgrid(G, CDIV(C, 64));
        k_pool_full<<<pgrid, 64, 0, stream>>>(gcn_out, gstart, gfeat);
    }

    // ---- graph FC branch (fp32) ----
    {
        dim3 grid(CDIV(G, 64), CDIV(1500, 64));
        gemm_tiled<<<grid, gblock, 0, stream>>>(gfeat, W_fcg1, b_fcg1, g1,
                                                G, 1500, 1560, 1560, 1500, 1500, 1);
    }
    {
        dim3 grid(CDIV(G, 64), CDIV(128, 64));
        gemm_tiled<<<grid, gblock, 0, stream>>>(g1, W_fcg2, b_fcg2, xc,
                                                G, 128, 1500, 1500, 128, 384, 0);
    }

    // ---- protein branch 2 ----
    k_build_M<<<G, 256, 0, stream>>>(t2, Wc2, Mbuf);
    k_conv2<<<CDIV(G * 3872, 256), 256, 0, stream>>>(Mbuf, emb, bc2, xt2c);
    {
        dim3 grid(CDIV(G, 64), CDIV(128, 64));
        gemm_tiled<<<grid, gblock, 0, stream>>>(xt2c, W_fc2xt, b_fc2xt, xc + 256,
                                                G, 128, 3872, 3872, 128, 384, 0);
    }

    // ---- protein branch 1 ----
    k_conv1<<<CDIV(G * 544, 256), 256, 0, stream>>>(t1, Wc1, bc1, xt1c);
    {
        dim3 grid(CDIV(G, 64), CDIV(128, 64));
        gemm_tiled<<<grid, gblock, 0, stream>>>(xt1c, W_fc1xt, b_fc1xt, xc + 128,
                                                G, 128, 544, 544, 128, 384, 0);
    }

    // ---- head ----
    {
        dim3 grid(CDIV(G, 64), CDIV(1024, 64));
        gemm_tiled<<<grid, gblock, 0, stream>>>(xc, W_fc1, b_fc1, f1,
                                                G, 1024, 384, 384, 1024, 1024, 1);
    }
    {
        dim3 grid(CDIV(G, 64), CDIV(512, 64));
        gemm_tiled<<<grid, gblock, 0, stream>>>(f1, W_fc2, b_fc2, f2,
                                                G, 512, 1024, 1024, 512, 512, 1);
    }
    {
        dim3 grid(CDIV(G, 64), 1);
        gemm_tiled<<<grid, gblock, 0, stream>>>(f2, W_out, b_out, (float*)d_out,
                                                G, 1, 512, 512, 1, 1, 0);
    }
}

// Round 4
// 1715.385 us; speedup vs baseline: 3.2525x; 1.7551x over previous
//
#include <hip/hip_runtime.h>
#include <cstdio>
#include <cstdint>

#define CDIV(a,b) (((a)+(b)-1)/(b))

static const int N   = 50000;   // nodes
static const int NE0 = 150000;  // edges w/o self loops
static const int NE  = 200000;  // edges with self loops
static const int H   = 10;      // heads
static const int F   = 78;      // per-head features
static const int C   = 780;     // H*F
static const int G   = 128;     // graphs
static const int KP_GAT = 96;   // 78 padded to 3*32
static const int KP_GCN = 800;  // 780 padded to 25*32

typedef __attribute__((ext_vector_type(8))) short bf16x8;
typedef __attribute__((ext_vector_type(4))) float f32x4;
typedef __attribute__((ext_vector_type(8))) unsigned short us8;

__device__ __forceinline__ float bf2f(unsigned short u) {
    return __uint_as_float(((unsigned int)u) << 16);
}
__device__ __forceinline__ unsigned short f2bf(float f) {
    unsigned int u = __float_as_uint(f);
    u = (u + 0x7fff + ((u >> 16) & 1)) >> 16;   // RNE
    return (unsigned short)u;
}

// ---------------------------------------------------------------------------
// bf16 MFMA GEMM: C[M,Nn] = A[M,K] @ B[K,Nn], A bf16 [M][lda] (lda=Kpad),
// Bt bf16 [Nn][ldb] (B transposed, ldb=Kpad), out bf16 [M][ldc].
// Block 256 thr = 4 waves (2x2), tile 128x128, BK=32.
// ---------------------------------------------------------------------------
__global__ __launch_bounds__(256)
void gemm_mfma(const unsigned short* __restrict__ A,
               const unsigned short* __restrict__ Bt,
               unsigned short* __restrict__ Cb,
               int M, int Nn, int kSteps, int lda, int ldb, int ldc)
{
    __shared__ unsigned short As[128][40];   // +8 pad: 2-way bank pattern (free)
    __shared__ unsigned short Bs[128][40];
    const int tid = threadIdx.x;
    const int lane = tid & 63;
    const int wave = tid >> 6;
    const int wm = (wave >> 1) * 64, wn = (wave & 1) * 64;
    const int bm = blockIdx.x * 128, bn = blockIdx.y * 128;

    f32x4 acc[4][4] = {};

    const int lrow = tid >> 2;        // 0..63
    const int lk   = (tid & 3) * 8;   // 0,8,16,24
    const int mrow = lane & 15, quad = lane >> 4;

    for (int ks = 0; ks < kSteps; ks++) {
        const int k0 = ks * 32;
        {   // clamped loads; garbage rows discarded by store guard
            int r0 = min(bm + lrow, M - 1);
            int r1 = min(bm + lrow + 64, M - 1);
            *(us8*)&As[lrow][lk]      = *(const us8*)&A[(size_t)r0 * lda + k0 + lk];
            *(us8*)&As[lrow + 64][lk] = *(const us8*)&A[(size_t)r1 * lda + k0 + lk];
            int n0 = min(bn + lrow, Nn - 1);
            int n1 = min(bn + lrow + 64, Nn - 1);
            *(us8*)&Bs[lrow][lk]      = *(const us8*)&Bt[(size_t)n0 * ldb + k0 + lk];
            *(us8*)&Bs[lrow + 64][lk] = *(const us8*)&Bt[(size_t)n1 * ldb + k0 + lk];
        }
        __syncthreads();
        bf16x8 af[4], bfr[4];
#pragma unroll
        for (int i = 0; i < 4; i++) {
            af[i]  = *(const bf16x8*)&As[wm + i * 16 + mrow][quad * 8];
            bfr[i] = *(const bf16x8*)&Bs[wn + i * 16 + mrow][quad * 8];
        }
#pragma unroll
        for (int i = 0; i < 4; i++)
#pragma unroll
            for (int j = 0; j < 4; j++)
                acc[i][j] = __builtin_amdgcn_mfma_f32_16x16x32_bf16(af[i], bfr[j], acc[i][j], 0, 0, 0);
        __syncthreads();
    }

    // epilogue: C/D layout col=lane&15, row=quad*4+reg  [m89-verified]
#pragma unroll
    for (int i = 0; i < 4; i++) {
#pragma unroll
        for (int j = 0; j < 4; j++) {
            int col = bn + wn + j * 16 + mrow;
            if (col >= Nn) continue;
#pragma unroll
            for (int r = 0; r < 4; r++) {
                int row = bm + wm + i * 16 + quad * 4 + r;
                if (row >= M) continue;
                Cb[(size_t)row * ldc + col] = f2bf(acc[i][j][r]);
            }
        }
    }
}

// ---------------------------------------------------------------------------
// Row-parallel fp32 GEMM for tiny-M layers: grid (M, col-chunks of 256).
// A row staged in LDS; each thread owns one output column (coalesced B reads).
// ---------------------------------------------------------------------------
__global__ __launch_bounds__(256)
void gemm_rows(const float* __restrict__ A, const float* __restrict__ B,
               const float* __restrict__ bias, float* __restrict__ Cc,
               int Nn, int K, int lda, int ldb, int ldc, int relu)
{
    __shared__ float a_sh[3872];   // max K across FC layers
    const int m = blockIdx.x;
    const int tid = threadIdx.x;
    for (int k = tid; k < K; k += 256) a_sh[k] = A[(size_t)m * lda + k];
    __syncthreads();
    int col = blockIdx.y * 256 + tid;
    if (col >= Nn) return;
    float acc = bias[col];
    const float* bp = B + col;
#pragma unroll 8
    for (int k = 0; k < K; k++) acc += a_sh[k] * bp[(size_t)k * ldb];
    if (relu) acc = fmaxf(acc, 0.f);
    Cc[(size_t)m * ldc + col] = acc;
}

// final [G,512] @ [512,1] + b  -> d_out; one block (64 lanes) per graph
__global__ void k_fc_out(const float* __restrict__ f2, const float* __restrict__ W,
                         const float* __restrict__ b, float* __restrict__ out)
{
    int g = blockIdx.x, lane = threadIdx.x;
    float acc = 0.f;
    for (int k = lane; k < 512; k += 64) acc += f2[g * 512 + k] * W[k];
#pragma unroll
    for (int off = 32; off > 0; off >>= 1) acc += __shfl_down(acc, off, 64);
    if (lane == 0) out[g] = acc + b[0];
}

// ---------------------------------------------------------------------------
// casts
// ---------------------------------------------------------------------------
__global__ void k_cast_pad_x(const float* __restrict__ x, unsigned short* __restrict__ xb)
{
    int idx = blockIdx.x * blockDim.x + threadIdx.x;
    if (idx >= N * KP_GAT) return;
    int n = idx / KP_GAT, k = idx % KP_GAT;
    float v = (k < F) ? x[(size_t)n * F + k] : 0.f;
    xb[idx] = f2bf(v);
}

// W[K][Nn] row-major fp32 -> Wt[Nn][Kpad] bf16 (transpose + zero-pad)
__global__ void k_transpose_cast(const float* __restrict__ W, unsigned short* __restrict__ Wt,
                                 int K, int Nn, int Kpad)
{
    int idx = blockIdx.x * blockDim.x + threadIdx.x;
    if (idx >= Nn * Kpad) return;
    int n = idx / Kpad, k = idx % Kpad;
    float v = (k < K) ? W[(size_t)k * Nn + n] : 0.f;
    Wt[idx] = f2bf(v);
}

// ---------------------------------------------------------------------------
// V_s[k,h] = sum_f W_gat[k, h*F+f] * att_src[h,f]  (78x10), same for V_d.
// ---------------------------------------------------------------------------
__global__ void k_Vsd(const float* __restrict__ W_gat, const float* __restrict__ att_src,
                      const float* __restrict__ att_dst, float* __restrict__ V_s,
                      float* __restrict__ V_d)
{
    int idx = blockIdx.x * blockDim.x + threadIdx.x;
    if (idx >= F * H) return;
    int k = idx / H, h = idx % H;
    const float* wr = W_gat + (size_t)k * C + h * F;
    const float* as = att_src + h * F;
    const float* ad = att_dst + h * F;
    float s = 0.f, d = 0.f;
    for (int f = 0; f < F; f++) { float w = wr[f]; s += w * as[f]; d += w * ad[f]; }
    V_s[idx] = s; V_d[idx] = d;
}

__global__ void k_ascores(const float* __restrict__ x, const float* __restrict__ V_s,
                          const float* __restrict__ V_d, float* __restrict__ a_s,
                          float* __restrict__ a_d)
{
    __shared__ float Vs[F * H], Vd[F * H];
    int t = threadIdx.x;
    for (int i = t; i < F * H; i += 256) { Vs[i] = V_s[i]; Vd[i] = V_d[i]; }
    __syncthreads();
    int n = blockIdx.x * 256 + t;
    if (n >= N) return;
    const float* xr = x + (size_t)n * F;
    float accs[H] = {}, accd[H] = {};
    for (int k = 0; k < F; k++) {
        float xv = xr[k];
        const float* vs = &Vs[k * H];
        const float* vd = &Vd[k * H];
#pragma unroll
        for (int h = 0; h < H; h++) { accs[h] += xv * vs[h]; accd[h] += xv * vd[h]; }
    }
    for (int h = 0; h < H; h++) { a_s[n * H + h] = accs[h]; a_d[n * H + h] = accd[h]; }
}

// ---------------------------------------------------------------------------
// CSR build
// ---------------------------------------------------------------------------
__global__ void count_deg(const int* __restrict__ ei, int* __restrict__ deg)
{
    int e = blockIdx.x * blockDim.x + threadIdx.x;
    if (e >= NE) return;
    int d = (e < NE0) ? ei[NE0 + e] : (e - NE0);
    atomicAdd(&deg[d], 1);
}

__global__ void scan_int(const int* __restrict__ cnt, int* __restrict__ row_start, int n)
{
    __shared__ int partial[1024];
    int tid = threadIdx.x;
    int per = CDIV(n, 1024);
    int start = tid * per, end = min(start + per, n);
    int sum = 0;
    for (int i = start; i < end; i++) sum += cnt[i];
    partial[tid] = sum;
    __syncthreads();
    for (int off = 1; off < 1024; off *= 2) {
        int v = (tid >= off) ? partial[tid - off] : 0;
        __syncthreads();
        partial[tid] += v;
        __syncthreads();
    }
    int base = (tid > 0) ? partial[tid - 1] : 0;
    for (int i = start; i < end; i++) { row_start[i] = base; base += cnt[i]; }
    if (tid == 1023) row_start[n] = base;
}

__global__ void fill_csr(const int* __restrict__ ei, const int* __restrict__ row_start,
                         int* __restrict__ fill_cnt, int* __restrict__ edge_list)
{
    int e = blockIdx.x * blockDim.x + threadIdx.x;
    if (e >= NE) return;
    int d = (e < NE0) ? ei[NE0 + e] : (e - NE0);
    int pos = row_start[d] + atomicAdd(&fill_cnt[d], 1);
    edge_list[pos] = e;
}

__global__ void k_graph_cnt(const int* __restrict__ batch, int* __restrict__ gcnt)
{
    int n = blockIdx.x * blockDim.x + threadIdx.x;
    if (n >= N) return;
    atomicAdd(&gcnt[batch[n]], 1);
}

// ---------------------------------------------------------------------------
// GAT softmax
// ---------------------------------------------------------------------------
__global__ void k_softmax_stats(const int* __restrict__ ei, const int* __restrict__ row_start,
                                const int* __restrict__ edge_list,
                                const float* __restrict__ a_s, const float* __restrict__ a_d,
                                float* __restrict__ m_ns, float* __restrict__ s_ns)
{
    int idx = blockIdx.x * blockDim.x + threadIdx.x;
    if (idx >= N * H) return;
    int n = idx / H, h = idx % H;
    float ad = a_d[idx];
    int rs = row_start[n], re = row_start[n + 1];
    float m = -INFINITY, s = 0.f;
    for (int i = rs; i < re; i++) {
        int e = edge_list[i];
        int sr = (e < NE0) ? ei[e] : (e - NE0);
        float ev = a_s[sr * H + h] + ad;
        ev = (ev > 0.f) ? ev : 0.2f * ev;
        if (ev <= m) {
            s += expf(ev - m);
        } else {
            s = s * expf(m - ev) + 1.f;
            m = ev;
        }
    }
    m_ns[idx] = m;
    s_ns[idx] = s;
}

__global__ void k_alpha(const int* __restrict__ ei, const float* __restrict__ a_s,
                        const float* __restrict__ a_d, const float* __restrict__ m_ns,
                        const float* __restrict__ s_ns, float* __restrict__ alpha)
{
    int idx = blockIdx.x * blockDim.x + threadIdx.x;
    if (idx >= NE * H) return;
    int e = idx / H, h = idx % H;
    int sr = (e < NE0) ? ei[e] : (e - NE0);
    int ds = (e < NE0) ? ei[NE0 + e] : (e - NE0);
    float ev = a_s[sr * H + h] + a_d[ds * H + h];
    ev = (ev > 0.f) ? ev : 0.2f * ev;
    alpha[idx] = expf(ev - m_ns[ds * H + h]) / (s_ns[ds * H + h] + 1e-16f);
}

// ---------------------------------------------------------------------------
// GAT aggregation: h1 bf16 [N][780] -> gat_out bf16 [N][800] (padded)
// ---------------------------------------------------------------------------
__global__ void gat_agg_full(const unsigned short* __restrict__ h1, const float* __restrict__ alpha,
                             const int* __restrict__ ei, const int* __restrict__ row_start,
                             const int* __restrict__ edge_list, const float* __restrict__ b_gat,
                             unsigned short* __restrict__ out)
{
    int n = blockIdx.x;
    int rs = row_start[n], re = row_start[n + 1];
    for (int c = threadIdx.x; c < KP_GCN; c += 256) {
        float r = 0.f;
        if (c < C) {
            int h = c / F;
            float acc = 0.f;
            for (int i = rs; i < re; i++) {
                int e = edge_list[i];
                int sr = (e < NE0) ? ei[e] : (e - NE0);
                acc += alpha[e * H + h] * bf2f(h1[(size_t)sr * C + c]);
            }
            r = fmaxf(acc + b_gat[c], 0.f);
        }
        out[(size_t)n * KP_GCN + c] = f2bf(r);
    }
}

__global__ void k_dinv(const int* __restrict__ deg, float* __restrict__ dinv)
{
    int n = blockIdx.x * blockDim.x + threadIdx.x;
    if (n >= N) return;
    int d = deg[n];
    dinv[n] = (d > 0) ? 1.f / sqrtf((float)d) : 0.f;
}

__global__ void gcn_agg_full(const unsigned short* __restrict__ h2, const float* __restrict__ dinv,
                             const int* __restrict__ ei, const int* __restrict__ row_start,
                             const int* __restrict__ edge_list, const float* __restrict__ b_gcn,
                             unsigned short* __restrict__ out)
{
    int n = blockIdx.x;
    float dn = dinv[n];
    int rs = row_start[n], re = row_start[n + 1];
    for (int c = threadIdx.x; c < C; c += 256) {
        float acc = 0.f;
        for (int i = rs; i < re; i++) {
            int e = edge_list[i];
            int sr = (e < NE0) ? ei[e] : (e - NE0);
            acc += dinv[sr] * bf2f(h2[(size_t)sr * C + c]);
        }
        out[(size_t)n * C + c] = f2bf(fmaxf(acc * dn + b_gcn[c], 0.f));
    }
}

__global__ void k_pool_full(const unsigned short* __restrict__ hh, const int* __restrict__ gstart,
                            float* __restrict__ gfeat)
{
    int g = blockIdx.x;
    int c = blockIdx.y * 64 + threadIdx.x;
    if (c >= C) return;
    int s = gstart[g], e = gstart[g + 1];
    float mx = 0.f, sum = 0.f;   // post-relu values >= 0
    for (int n = s; n < e; n++) {
        float v = bf2f(hh[(size_t)n * C + c]);
        mx = fmaxf(mx, v);
        sum += v;
    }
    float cnt = (float)(e - s);
    gfeat[g * 1560 + c] = mx;
    gfeat[g * 1560 + 780 + c] = sum / fmaxf(cnt, 1.f);
}

// ---------------------------------------------------------------------------
// protein branches
// ---------------------------------------------------------------------------
__global__ void k_build_M(const int* __restrict__ t2, const float* __restrict__ Wc2,
                          float* __restrict__ Mbuf)
{
    __shared__ float Ml[26 * 256];
    int b = blockIdx.x, t = threadIdx.x;
    for (int j = t; j < 26 * 256; j += 256) Ml[j] = 0.f;
    __syncthreads();
    int o = t >> 3, k = t & 7;
    const int* tb = t2 + b * 1000;
    for (int cc = 0; cc < 1000; cc++) {
        int tok = tb[cc];
        Ml[tok * 256 + t] += Wc2[o * 8000 + cc * 8 + k];
    }
    __syncthreads();
    float* Mb = Mbuf + (size_t)b * (26 * 256);
    for (int j = t; j < 26 * 256; j += 256) Mb[j] = Ml[j];
}

__global__ void k_conv2(const float* __restrict__ Mbuf, const float* __restrict__ emb,
                        const float* __restrict__ bc2, float* __restrict__ xt2c)
{
    int idx = blockIdx.x * blockDim.x + threadIdx.x;
    if (idx >= G * 3872) return;
    int b = idx / 3872, r = idx % 3872;
    int o = r / 121, l = r % 121;
    const float* Mb = Mbuf + (size_t)b * (26 * 256);
    float acc = bc2[o];
    for (int t = 0; t < 26; t++) {
        const float* mrow = Mb + t * 256 + o * 8;
        const float* erow = emb + t * 128 + l;
#pragma unroll
        for (int k = 0; k < 8; k++) acc += mrow[k] * erow[k];
    }
    xt2c[idx] = acc;
}

__global__ void k_conv1(const float* __restrict__ t1, const float* __restrict__ Wc1,
                        const float* __restrict__ bc1, float* __restrict__ xt1c)
{
    int idx = blockIdx.x * blockDim.x + threadIdx.x;
    if (idx >= G * 544) return;
    int b = idx / 544, r = idx % 544;
    int o = r / 17, l = r % 17;
    float acc = bc1[o];
    const float* xb = t1 + b * 480;
    const float* wo = Wc1 + o * 160;
    for (int cc = 0; cc < 20; cc++) {
        const float* xr = xb + cc * 24 + l;
        const float* wr = wo + cc * 8;
#pragma unroll
        for (int k = 0; k < 8; k++) acc += xr[k] * wr[k];
    }
    xt1c[idx] = acc;
}

// ---------------------------------------------------------------------------
extern "C" void kernel_launch(void* const* d_in, const int* in_sizes, int n_in,
                              void* d_out, int out_size, void* d_ws, size_t ws_size,
                              hipStream_t stream)
{
    const float* x       = (const float*)d_in[0];
    const int*   ei      = (const int*)  d_in[1];
    const int*   batch   = (const int*)  d_in[2];
    const float* t1      = (const float*)d_in[3];
    const int*   t2      = (const int*)  d_in[4];
    const float* W_gat   = (const float*)d_in[5];
    const float* att_src = (const float*)d_in[6];
    const float* att_dst = (const float*)d_in[7];
    const float* b_gat   = (const float*)d_in[8];
    const float* W_gcn   = (const float*)d_in[9];
    const float* b_gcn   = (const float*)d_in[10];
    const float* W_fcg1  = (const float*)d_in[11];
    const float* b_fcg1  = (const float*)d_in[12];
    const float* W_fcg2  = (const float*)d_in[13];
    const float* b_fcg2  = (const float*)d_in[14];
    const float* emb     = (const float*)d_in[15];
    const float* Wc2     = (const float*)d_in[16];
    const float* bc2     = (const float*)d_in[17];
    const float* W_fc2xt = (const float*)d_in[18];
    const float* b_fc2xt = (const float*)d_in[19];
    const float* Wc1     = (const float*)d_in[20];
    const float* bc1     = (const float*)d_in[21];
    const float* W_fc1xt = (const float*)d_in[22];
    const float* b_fc1xt = (const float*)d_in[23];
    const float* W_fc1   = (const float*)d_in[24];
    const float* b_fc1   = (const float*)d_in[25];
    const float* W_fc2   = (const float*)d_in[26];
    const float* b_fc2   = (const float*)d_in[27];
    const float* W_out   = (const float*)d_in[28];
    const float* b_out   = (const float*)d_in[29];

    char* wsb = (char*)d_ws;
    size_t off = 0;
    auto alloc = [&](size_t bytes) -> char* {
        char* p = wsb + off;
        off += (bytes + 255) & ~(size_t)255;
        return p;
    };

    unsigned short* h_buf   = (unsigned short*)alloc((size_t)N * C * 2);       // h1 then h2
    unsigned short* gat_out = (unsigned short*)alloc((size_t)N * KP_GCN * 2);  // reused as gcn_out
    unsigned short* xb      = (unsigned short*)alloc((size_t)N * KP_GAT * 2);
    unsigned short* Wgat_t  = (unsigned short*)alloc((size_t)C * KP_GAT * 2);
    unsigned short* Wgcn_t  = (unsigned short*)alloc((size_t)C * KP_GCN * 2);
    float* V_s    = (float*)alloc((size_t)F * H * 4);
    float* V_d    = (float*)alloc((size_t)F * H * 4);
    float* a_s    = (float*)alloc((size_t)N * H * 4);
    float* a_d    = (float*)alloc((size_t)N * H * 4);
    float* m_ns   = (float*)alloc((size_t)N * H * 4);
    float* s_ns   = (float*)alloc((size_t)N * H * 4);
    float* alpha  = (float*)alloc((size_t)NE * H * 4);
    float* dinv   = (float*)alloc((size_t)N * 4);
    float* gfeat  = (float*)alloc((size_t)G * 1560 * 4);
    float* g1     = (float*)alloc((size_t)G * 1500 * 4);
    float* Mbuf   = (float*)alloc((size_t)G * 26 * 256 * 4);
    float* xt2c   = (float*)alloc((size_t)G * 3872 * 4);
    float* xt1c   = (float*)alloc((size_t)G * 544 * 4);
    float* xc     = (float*)alloc((size_t)G * 384 * 4);
    float* f1     = (float*)alloc((size_t)G * 1024 * 4);
    float* f2     = (float*)alloc((size_t)G * 512 * 4);
    int* deg       = (int*)alloc((size_t)N * 4);
    int* row_start = (int*)alloc((size_t)(N + 1) * 4);
    int* fill_cnt  = (int*)alloc((size_t)N * 4);
    int* edge_list = (int*)alloc((size_t)NE * 4);
    int* gcnt      = (int*)alloc((size_t)G * 4);
    int* gstart    = (int*)alloc((size_t)(G + 1) * 4);

    if (off > ws_size) {
        fprintf(stderr, "kernel_launch: workspace too small: need %zu have %zu\n", off, ws_size);
        return;
    }

    hipMemsetAsync(deg, 0, (size_t)N * 4, stream);
    hipMemsetAsync(fill_cnt, 0, (size_t)N * 4, stream);
    hipMemsetAsync(gcnt, 0, (size_t)G * 4, stream);

    // ---- casts ----
    k_cast_pad_x<<<CDIV(N * KP_GAT, 256), 256, 0, stream>>>(x, xb);
    k_transpose_cast<<<CDIV(C * KP_GAT, 256), 256, 0, stream>>>(W_gat, Wgat_t, F, C, KP_GAT);
    k_transpose_cast<<<CDIV(C * KP_GCN, 256), 256, 0, stream>>>(W_gcn, Wgcn_t, C, C, KP_GCN);

    // ---- attention logits ----
    k_Vsd<<<CDIV(F * H, 256), 256, 0, stream>>>(W_gat, att_src, att_dst, V_s, V_d);
    k_ascores<<<CDIV(N, 256), 256, 0, stream>>>(x, V_s, V_d, a_s, a_d);

    // ---- CSR + graph ranges ----
    count_deg<<<CDIV(NE, 256), 256, 0, stream>>>(ei, deg);
    scan_int<<<1, 1024, 0, stream>>>(deg, row_start, N);
    fill_csr<<<CDIV(NE, 256), 256, 0, stream>>>(ei, row_start, fill_cnt, edge_list);
    k_graph_cnt<<<CDIV(N, 256), 256, 0, stream>>>(batch, gcnt);
    scan_int<<<1, 1024, 0, stream>>>(gcnt, gstart, G);

    // ---- softmax ----
    k_softmax_stats<<<CDIV(N * H, 256), 256, 0, stream>>>(ei, row_start, edge_list, a_s, a_d, m_ns, s_ns);
    k_alpha<<<CDIV(NE * H, 256), 256, 0, stream>>>(ei, a_s, a_d, m_ns, s_ns, alpha);
    k_dinv<<<CDIV(N, 256), 256, 0, stream>>>(deg, dinv);

    // ---- GAT ----
    {
        dim3 grid(CDIV(N, 128), CDIV(C, 128));
        gemm_mfma<<<grid, 256, 0, stream>>>(xb, Wgat_t, h_buf, N, C, KP_GAT / 32, KP_GAT, KP_GAT, C);
    }
    gat_agg_full<<<N, 256, 0, stream>>>(h_buf, alpha, ei, row_start, edge_list, b_gat, gat_out);

    // ---- GCN ----
    {
        dim3 grid(CDIV(N, 128), CDIV(C, 128));
        gemm_mfma<<<grid, 256, 0, stream>>>(gat_out, Wgcn_t, h_buf, N, C, KP_GCN / 32, KP_GCN, KP_GCN, C);
    }
    unsigned short* gcn_out = gat_out;   // dead after GEMM, reuse
    gcn_agg_full<<<N, 256, 0, stream>>>(h_buf, dinv, ei, row_start, edge_list, b_gcn, gcn_out);
    {
        dim3 pgrid(G, CDIV(C, 64));
        k_pool_full<<<pgrid, 64, 0, stream>>>(gcn_out, gstart, gfeat);
    }

    // ---- graph FC branch (row-parallel fp32) ----
    {
        dim3 grid(G, CDIV(1500, 256));
        gemm_rows<<<grid, 256, 0, stream>>>(gfeat, W_fcg1, b_fcg1, g1, 1500, 1560, 1560, 1500, 1500, 1);
    }
    {
        dim3 grid(G, 1);
        gemm_rows<<<grid, 256, 0, stream>>>(g1, W_fcg2, b_fcg2, xc, 128, 1500, 1500, 128, 384, 0);
    }

    // ---- protein branch 2 ----
    k_build_M<<<G, 256, 0, stream>>>(t2, Wc2, Mbuf);
    k_conv2<<<CDIV(G * 3872, 256), 256, 0, stream>>>(Mbuf, emb, bc2, xt2c);
    {
        dim3 grid(G, 1);
        gemm_rows<<<grid, 256, 0, stream>>>(xt2c, W_fc2xt, b_fc2xt, xc + 256, 128, 3872, 3872, 128, 384, 0);
    }

    // ---- protein branch 1 ----
    k_conv1<<<CDIV(G * 544, 256), 256, 0, stream>>>(t1, Wc1, bc1, xt1c);
    {
        dim3 grid(G, 1);
        gemm_rows<<<grid, 256, 0, stream>>>(xt1c, W_fc1xt, b_fc1xt, xc + 128, 128, 544, 544, 128, 384, 0);
    }

    // ---- head ----
    {
        dim3 grid(G, CDIV(1024, 256));
        gemm_rows<<<grid, 256, 0, stream>>>(xc, W_fc1, b_fc1, f1, 1024, 384, 384, 1024, 1024, 1);
    }
    {
        dim3 grid(G, CDIV(512, 256));
        gemm_rows<<<grid, 256, 0, stream>>>(f1, W_fc2, b_fc2, f2, 512, 1024, 1024, 512, 512, 1);
    }
    k_fc_out<<<G, 64, 0, stream>>>(f2, W_out, b_out, (float*)d_out);
}

// Round 5
// 1562.637 us; speedup vs baseline: 3.5704x; 1.0978x over previous
//
#include <hip/hip_runtime.h>
#include <cstdio>
#include <cstdint>

#define CDIV(a,b) (((a)+(b)-1)/(b))

static const int N   = 50000;   // nodes
static const int NE0 = 150000;  // edges w/o self loops
static const int NE  = 200000;  // edges with self loops
static const int H   = 10;      // heads
static const int F   = 78;      // per-head features
static const int C   = 780;     // H*F
static const int G   = 128;     // graphs
static const int KP_GAT = 96;   // 78 padded to 3*32
static const int KP_GCN = 800;  // 780 padded to 25*32

typedef __attribute__((ext_vector_type(8))) short bf16x8;
typedef __attribute__((ext_vector_type(4))) float f32x4;
typedef __attribute__((ext_vector_type(8))) unsigned short us8;

__device__ __forceinline__ float bf2f(unsigned short u) {
    return __uint_as_float(((unsigned int)u) << 16);
}
__device__ __forceinline__ unsigned short f2bf(float f) {
    unsigned int u = __float_as_uint(f);
    u = (u + 0x7fff + ((u >> 16) & 1)) >> 16;   // RNE
    return (unsigned short)u;
}

// ---------------------------------------------------------------------------
// bf16 MFMA GEMM: C[M,Nn] = A[M,K] @ B[K,Nn] (+bias, optional relu).
// A bf16 [M][lda], Bt bf16 [Nn][ldb] (B transposed), out bf16 [M][ldc].
// Block 256 thr = 4 waves (2x2), tile 128x128, BK=32. lda/ldb mult of 8,
// K-pad zeros required in A (B pad columns then don't matter).
// ---------------------------------------------------------------------------
__global__ __launch_bounds__(256)
void gemm_mfma(const unsigned short* __restrict__ A,
               const unsigned short* __restrict__ Bt,
               unsigned short* __restrict__ Cb,
               const float* __restrict__ bias, int relu,
               int M, int Nn, int kSteps, int lda, int ldb, int ldc)
{
    __shared__ unsigned short As[128][40];   // +8 pad: 2-way bank pattern (free)
    __shared__ unsigned short Bs[128][40];
    const int tid = threadIdx.x;
    const int lane = tid & 63;
    const int wave = tid >> 6;
    const int wm = (wave >> 1) * 64, wn = (wave & 1) * 64;
    const int bm = blockIdx.x * 128, bn = blockIdx.y * 128;

    f32x4 acc[4][4] = {};

    const int lrow = tid >> 2;        // 0..63
    const int lk   = (tid & 3) * 8;   // 0,8,16,24
    const int mrow = lane & 15, quad = lane >> 4;

    for (int ks = 0; ks < kSteps; ks++) {
        const int k0 = ks * 32;
        {   // clamped loads; garbage rows discarded by store guard
            int r0 = min(bm + lrow, M - 1);
            int r1 = min(bm + lrow + 64, M - 1);
            *(us8*)&As[lrow][lk]      = *(const us8*)&A[(size_t)r0 * lda + k0 + lk];
            *(us8*)&As[lrow + 64][lk] = *(const us8*)&A[(size_t)r1 * lda + k0 + lk];
            int n0 = min(bn + lrow, Nn - 1);
            int n1 = min(bn + lrow + 64, Nn - 1);
            *(us8*)&Bs[lrow][lk]      = *(const us8*)&Bt[(size_t)n0 * ldb + k0 + lk];
            *(us8*)&Bs[lrow + 64][lk] = *(const us8*)&Bt[(size_t)n1 * ldb + k0 + lk];
        }
        __syncthreads();
        bf16x8 af[4], bfr[4];
#pragma unroll
        for (int i = 0; i < 4; i++) {
            af[i]  = *(const bf16x8*)&As[wm + i * 16 + mrow][quad * 8];
            bfr[i] = *(const bf16x8*)&Bs[wn + i * 16 + mrow][quad * 8];
        }
#pragma unroll
        for (int i = 0; i < 4; i++)
#pragma unroll
            for (int j = 0; j < 4; j++)
                acc[i][j] = __builtin_amdgcn_mfma_f32_16x16x32_bf16(af[i], bfr[j], acc[i][j], 0, 0, 0);
        __syncthreads();
    }

    // epilogue: C/D layout col=lane&15, row=quad*4+reg  [m89-verified]
#pragma unroll
    for (int i = 0; i < 4; i++) {
#pragma unroll
        for (int j = 0; j < 4; j++) {
            int col = bn + wn + j * 16 + mrow;
            if (col >= Nn) continue;
            float bv = bias ? bias[col] : 0.f;
#pragma unroll
            for (int r = 0; r < 4; r++) {
                int row = bm + wm + i * 16 + quad * 4 + r;
                if (row >= M) continue;
                float v = acc[i][j][r] + bv;
                if (relu) v = fmaxf(v, 0.f);
                Cb[(size_t)row * ldc + col] = f2bf(v);
            }
        }
    }
}

// final [G,512]bf16 @ [512,1] + b -> d_out; one block (64 lanes) per graph
__global__ void k_fc_out(const unsigned short* __restrict__ f2, const float* __restrict__ W,
                         const float* __restrict__ b, float* __restrict__ out)
{
    int g = blockIdx.x, lane = threadIdx.x;
    float acc = 0.f;
    for (int k = lane; k < 512; k += 64) acc += bf2f(f2[g * 512 + k]) * W[k];
#pragma unroll
    for (int off = 32; off > 0; off >>= 1) acc += __shfl_down(acc, off, 64);
    if (lane == 0) out[g] = acc + b[0];
}

// ---------------------------------------------------------------------------
// casts / transposes
// ---------------------------------------------------------------------------
__global__ void k_cast_pad_x(const float* __restrict__ x, unsigned short* __restrict__ xb)
{
    int idx = blockIdx.x * blockDim.x + threadIdx.x;
    if (idx >= N * KP_GAT) return;
    int n = idx / KP_GAT, k = idx % KP_GAT;
    float v = (k < F) ? x[(size_t)n * F + k] : 0.f;
    xb[idx] = f2bf(v);
}

// generic fp32 [M][K] -> bf16 [M][Kpad] zero-padded
__global__ void k_cast_pad(const float* __restrict__ src, unsigned short* __restrict__ dst,
                           int M, int K, int Kpad)
{
    int idx = blockIdx.x * blockDim.x + threadIdx.x;
    if (idx >= M * Kpad) return;
    int m = idx / Kpad, k = idx % Kpad;
    dst[idx] = f2bf((k < K) ? src[(size_t)m * K + k] : 0.f);
}

// LDS-tiled transpose-cast: W[K][Nn] fp32 -> Wt[Nn][Kpad] bf16 (pads zeroed).
// block (32,8), grid (CDIV(Kpad,32), CDIV(Nn,32)); coalesced reads AND writes.
__global__ void k_transpose_cast_t(const float* __restrict__ W, unsigned short* __restrict__ Wt,
                                   int K, int Nn, int Kpad)
{
    __shared__ float tile[32][33];
    int k0 = blockIdx.x * 32, n0 = blockIdx.y * 32;
    int tx = threadIdx.x, ty = threadIdx.y;
    for (int r = ty; r < 32; r += 8) {
        int k = k0 + r, n = n0 + tx;
        tile[r][tx] = (k < K && n < Nn) ? W[(size_t)k * Nn + n] : 0.f;
    }
    __syncthreads();
    for (int r = ty; r < 32; r += 8) {
        int n = n0 + r, k = k0 + tx;
        if (n < Nn && k < Kpad) Wt[(size_t)n * Kpad + k] = f2bf(tile[tx][r]);
    }
}

// ---------------------------------------------------------------------------
// V_s[k,h] = sum_f W_gat[k, h*F+f] * att_src[h,f]  (78x10), same for V_d.
// ---------------------------------------------------------------------------
__global__ void k_Vsd(const float* __restrict__ W_gat, const float* __restrict__ att_src,
                      const float* __restrict__ att_dst, float* __restrict__ V_s,
                      float* __restrict__ V_d)
{
    int idx = blockIdx.x * blockDim.x + threadIdx.x;
    if (idx >= F * H) return;
    int k = idx / H, h = idx % H;
    const float* wr = W_gat + (size_t)k * C + h * F;
    const float* as = att_src + h * F;
    const float* ad = att_dst + h * F;
    float s = 0.f, d = 0.f;
    for (int f = 0; f < F; f++) { float w = wr[f]; s += w * as[f]; d += w * ad[f]; }
    V_s[idx] = s; V_d[idx] = d;
}

__global__ void k_ascores(const float* __restrict__ x, const float* __restrict__ V_s,
                          const float* __restrict__ V_d, float* __restrict__ a_s,
                          float* __restrict__ a_d)
{
    __shared__ float Vs[F * H], Vd[F * H];
    int t = threadIdx.x;
    for (int i = t; i < F * H; i += 256) { Vs[i] = V_s[i]; Vd[i] = V_d[i]; }
    __syncthreads();
    int n = blockIdx.x * 256 + t;
    if (n >= N) return;
    const float* xr = x + (size_t)n * F;
    float accs[H] = {}, accd[H] = {};
    for (int k = 0; k < F; k++) {
        float xv = xr[k];
        const float* vs = &Vs[k * H];
        const float* vd = &Vd[k * H];
#pragma unroll
        for (int h = 0; h < H; h++) { accs[h] += xv * vs[h]; accd[h] += xv * vd[h]; }
    }
    for (int h = 0; h < H; h++) { a_s[n * H + h] = accs[h]; a_d[n * H + h] = accd[h]; }
}

// ---------------------------------------------------------------------------
// CSR build
// ---------------------------------------------------------------------------
__global__ void count_deg(const int* __restrict__ ei, int* __restrict__ deg)
{
    int e = blockIdx.x * blockDim.x + threadIdx.x;
    if (e >= NE) return;
    int d = (e < NE0) ? ei[NE0 + e] : (e - NE0);
    atomicAdd(&deg[d], 1);
}

__global__ void scan_int(const int* __restrict__ cnt, int* __restrict__ row_start, int n)
{
    __shared__ int partial[1024];
    int tid = threadIdx.x;
    int per = CDIV(n, 1024);
    int start = tid * per, end = min(start + per, n);
    int sum = 0;
    for (int i = start; i < end; i++) sum += cnt[i];
    partial[tid] = sum;
    __syncthreads();
    for (int off = 1; off < 1024; off *= 2) {
        int v = (tid >= off) ? partial[tid - off] : 0;
        __syncthreads();
        partial[tid] += v;
        __syncthreads();
    }
    int base = (tid > 0) ? partial[tid - 1] : 0;
    for (int i = start; i < end; i++) { row_start[i] = base; base += cnt[i]; }
    if (tid == 1023) row_start[n] = base;
}

__global__ void fill_csr(const int* __restrict__ ei, const int* __restrict__ row_start,
                         int* __restrict__ fill_cnt, int* __restrict__ edge_list)
{
    int e = blockIdx.x * blockDim.x + threadIdx.x;
    if (e >= NE) return;
    int d = (e < NE0) ? ei[NE0 + e] : (e - NE0);
    int pos = row_start[d] + atomicAdd(&fill_cnt[d], 1);
    edge_list[pos] = e;
}

__global__ void k_graph_cnt(const int* __restrict__ batch, int* __restrict__ gcnt)
{
    int n = blockIdx.x * blockDim.x + threadIdx.x;
    if (n >= N) return;
    atomicAdd(&gcnt[batch[n]], 1);
}

// ---------------------------------------------------------------------------
// GAT softmax
// ---------------------------------------------------------------------------
__global__ void k_softmax_stats(const int* __restrict__ ei, const int* __restrict__ row_start,
                                const int* __restrict__ edge_list,
                                const float* __restrict__ a_s, const float* __restrict__ a_d,
                                float* __restrict__ m_ns, float* __restrict__ s_ns)
{
    int idx = blockIdx.x * blockDim.x + threadIdx.x;
    if (idx >= N * H) return;
    int n = idx / H, h = idx % H;
    float ad = a_d[idx];
    int rs = row_start[n], re = row_start[n + 1];
    float m = -INFINITY, s = 0.f;
    for (int i = rs; i < re; i++) {
        int e = edge_list[i];
        int sr = (e < NE0) ? ei[e] : (e - NE0);
        float ev = a_s[sr * H + h] + ad;
        ev = (ev > 0.f) ? ev : 0.2f * ev;
        if (ev <= m) {
            s += expf(ev - m);
        } else {
            s = s * expf(m - ev) + 1.f;
            m = ev;
        }
    }
    m_ns[idx] = m;
    s_ns[idx] = s;
}

__global__ void k_alpha(const int* __restrict__ ei, const float* __restrict__ a_s,
                        const float* __restrict__ a_d, const float* __restrict__ m_ns,
                        const float* __restrict__ s_ns, float* __restrict__ alpha)
{
    int idx = blockIdx.x * blockDim.x + threadIdx.x;
    if (idx >= NE * H) return;
    int e = idx / H, h = idx % H;
    int sr = (e < NE0) ? ei[e] : (e - NE0);
    int ds = (e < NE0) ? ei[NE0 + e] : (e - NE0);
    float ev = a_s[sr * H + h] + a_d[ds * H + h];
    ev = (ev > 0.f) ? ev : 0.2f * ev;
    alpha[idx] = expf(ev - m_ns[ds * H + h]) / (s_ns[ds * H + h] + 1e-16f);
}

// ---------------------------------------------------------------------------
// GAT aggregation: h1 bf16 [N][780] -> gat_out bf16 [N][800] (padded)
// ---------------------------------------------------------------------------
__global__ void gat_agg_full(const unsigned short* __restrict__ h1, const float* __restrict__ alpha,
                             const int* __restrict__ ei, const int* __restrict__ row_start,
                             const int* __restrict__ edge_list, const float* __restrict__ b_gat,
                             unsigned short* __restrict__ out)
{
    int n = blockIdx.x;
    int rs = row_start[n], re = row_start[n + 1];
    for (int c = threadIdx.x; c < KP_GCN; c += 256) {
        float r = 0.f;
        if (c < C) {
            int h = c / F;
            float acc = 0.f;
            for (int i = rs; i < re; i++) {
                int e = edge_list[i];
                int sr = (e < NE0) ? ei[e] : (e - NE0);
                acc += alpha[e * H + h] * bf2f(h1[(size_t)sr * C + c]);
            }
            r = fmaxf(acc + b_gat[c], 0.f);
        }
        out[(size_t)n * KP_GCN + c] = f2bf(r);
    }
}

__global__ void k_dinv(const int* __restrict__ deg, float* __restrict__ dinv)
{
    int n = blockIdx.x * blockDim.x + threadIdx.x;
    if (n >= N) return;
    int d = deg[n];
    dinv[n] = (d > 0) ? 1.f / sqrtf((float)d) : 0.f;
}

__global__ void gcn_agg_full(const unsigned short* __restrict__ h2, const float* __restrict__ dinv,
                             const int* __restrict__ ei, const int* __restrict__ row_start,
                             const int* __restrict__ edge_list, const float* __restrict__ b_gcn,
                             unsigned short* __restrict__ out)
{
    int n = blockIdx.x;
    float dn = dinv[n];
    int rs = row_start[n], re = row_start[n + 1];
    for (int c = threadIdx.x; c < C; c += 256) {
        float acc = 0.f;
        for (int i = rs; i < re; i++) {
            int e = edge_list[i];
            int sr = (e < NE0) ? ei[e] : (e - NE0);
            acc += dinv[sr] * bf2f(h2[(size_t)sr * C + c]);
        }
        out[(size_t)n * C + c] = f2bf(fmaxf(acc * dn + b_gcn[c], 0.f));
    }
}

__global__ void k_pool_full(const unsigned short* __restrict__ hh, const int* __restrict__ gstart,
                            float* __restrict__ gfeat)
{
    int g = blockIdx.x;
    int c = blockIdx.y * 64 + threadIdx.x;
    if (c >= C) return;
    int s = gstart[g], e = gstart[g + 1];
    float mx = 0.f, sum = 0.f;   // post-relu values >= 0
    for (int n = s; n < e; n++) {
        float v = bf2f(hh[(size_t)n * C + c]);
        mx = fmaxf(mx, v);
        sum += v;
    }
    float cnt = (float)(e - s);
    gfeat[g * 1560 + c] = mx;
    gfeat[g * 1560 + 780 + c] = sum / fmaxf(cnt, 1.f);
}

// ---------------------------------------------------------------------------
// protein branches (conv outputs written as bf16 GEMM operands)
// ---------------------------------------------------------------------------
__global__ void k_build_M(const int* __restrict__ t2, const float* __restrict__ Wc2,
                          float* __restrict__ Mbuf)
{
    __shared__ float Ml[26 * 256];
    int b = blockIdx.x, t = threadIdx.x;
    for (int j = t; j < 26 * 256; j += 256) Ml[j] = 0.f;
    __syncthreads();
    int o = t >> 3, k = t & 7;
    const int* tb = t2 + b * 1000;
    for (int cc = 0; cc < 1000; cc++) {
        int tok = tb[cc];
        Ml[tok * 256 + t] += Wc2[o * 8000 + cc * 8 + k];
    }
    __syncthreads();
    float* Mb = Mbuf + (size_t)b * (26 * 256);
    for (int j = t; j < 26 * 256; j += 256) Mb[j] = Ml[j];
}

__global__ void k_conv2(const float* __restrict__ Mbuf, const float* __restrict__ emb,
                        const float* __restrict__ bc2, unsigned short* __restrict__ xt2c)
{
    int idx = blockIdx.x * blockDim.x + threadIdx.x;
    if (idx >= G * 3872) return;
    int b = idx / 3872, r = idx % 3872;
    int o = r / 121, l = r % 121;
    const float* Mb = Mbuf + (size_t)b * (26 * 256);
    float acc = bc2[o];
    for (int t = 0; t < 26; t++) {
        const float* mrow = Mb + t * 256 + o * 8;
        const float* erow = emb + t * 128 + l;
#pragma unroll
        for (int k = 0; k < 8; k++) acc += mrow[k] * erow[k];
    }
    xt2c[idx] = f2bf(acc);
}

__global__ void k_conv1(const float* __restrict__ t1, const float* __restrict__ Wc1,
                        const float* __restrict__ bc1, unsigned short* __restrict__ xt1c)
{
    int idx = blockIdx.x * blockDim.x + threadIdx.x;
    if (idx >= G * 544) return;
    int b = idx / 544, r = idx % 544;
    int o = r / 17, l = r % 17;
    float acc = bc1[o];
    const float* xb = t1 + b * 480;
    const float* wo = Wc1 + o * 160;
    for (int cc = 0; cc < 20; cc++) {
        const float* xr = xb + cc * 24 + l;
        const float* wr = wo + cc * 8;
#pragma unroll
        for (int k = 0; k < 8; k++) acc += xr[k] * wr[k];
    }
    xt1c[idx] = f2bf(acc);
}

// ---------------------------------------------------------------------------
extern "C" void kernel_launch(void* const* d_in, const int* in_sizes, int n_in,
                              void* d_out, int out_size, void* d_ws, size_t ws_size,
                              hipStream_t stream)
{
    const float* x       = (const float*)d_in[0];
    const int*   ei      = (const int*)  d_in[1];
    const int*   batch   = (const int*)  d_in[2];
    const float* t1      = (const float*)d_in[3];
    const int*   t2      = (const int*)  d_in[4];
    const float* W_gat   = (const float*)d_in[5];
    const float* att_src = (const float*)d_in[6];
    const float* att_dst = (const float*)d_in[7];
    const float* b_gat   = (const float*)d_in[8];
    const float* W_gcn   = (const float*)d_in[9];
    const float* b_gcn   = (const float*)d_in[10];
    const float* W_fcg1  = (const float*)d_in[11];
    const float* b_fcg1  = (const float*)d_in[12];
    const float* W_fcg2  = (const float*)d_in[13];
    const float* b_fcg2  = (const float*)d_in[14];
    const float* emb     = (const float*)d_in[15];
    const float* Wc2     = (const float*)d_in[16];
    const float* bc2     = (const float*)d_in[17];
    const float* W_fc2xt = (const float*)d_in[18];
    const float* b_fc2xt = (const float*)d_in[19];
    const float* Wc1     = (const float*)d_in[20];
    const float* bc1     = (const float*)d_in[21];
    const float* W_fc1xt = (const float*)d_in[22];
    const float* b_fc1xt = (const float*)d_in[23];
    const float* W_fc1   = (const float*)d_in[24];
    const float* b_fc1   = (const float*)d_in[25];
    const float* W_fc2   = (const float*)d_in[26];
    const float* b_fc2   = (const float*)d_in[27];
    const float* W_out   = (const float*)d_in[28];
    const float* b_out   = (const float*)d_in[29];

    char* wsb = (char*)d_ws;
    size_t off = 0;
    auto alloc = [&](size_t bytes) -> char* {
        char* p = wsb + off;
        off += (bytes + 255) & ~(size_t)255;
        return p;
    };

    unsigned short* h_buf   = (unsigned short*)alloc((size_t)N * C * 2);       // h1 then h2
    unsigned short* gat_out = (unsigned short*)alloc((size_t)N * KP_GCN * 2);  // reused as gcn_out
    unsigned short* xb      = (unsigned short*)alloc((size_t)N * KP_GAT * 2);
    unsigned short* Wgat_t  = (unsigned short*)alloc((size_t)C * KP_GAT * 2);
    unsigned short* Wgcn_t  = (unsigned short*)alloc((size_t)C * KP_GCN * 2);
    // FC tail bf16 weights (transposed) + activations
    unsigned short* Wfcg1_t  = (unsigned short*)alloc((size_t)1500 * 1568 * 2);
    unsigned short* Wfcg2_t  = (unsigned short*)alloc((size_t)128 * 1504 * 2);
    unsigned short* Wfc2xt_t = (unsigned short*)alloc((size_t)128 * 3872 * 2);
    unsigned short* Wfc1xt_t = (unsigned short*)alloc((size_t)128 * 544 * 2);
    unsigned short* Wfc1_t   = (unsigned short*)alloc((size_t)1024 * 384 * 2);
    unsigned short* Wfc2_t   = (unsigned short*)alloc((size_t)512 * 1024 * 2);
    unsigned short* gfeat_b  = (unsigned short*)alloc((size_t)G * 1568 * 2);
    unsigned short* g1_b     = (unsigned short*)alloc((size_t)G * 1504 * 2);
    unsigned short* xt2c_b   = (unsigned short*)alloc((size_t)G * 3872 * 2);
    unsigned short* xt1c_b   = (unsigned short*)alloc((size_t)G * 544 * 2);
    unsigned short* xc_b     = (unsigned short*)alloc((size_t)G * 384 * 2);
    unsigned short* f1_b     = (unsigned short*)alloc((size_t)G * 1024 * 2);
    unsigned short* f2_b     = (unsigned short*)alloc((size_t)G * 512 * 2);
    float* V_s    = (float*)alloc((size_t)F * H * 4);
    float* V_d    = (float*)alloc((size_t)F * H * 4);
    float* a_s    = (float*)alloc((size_t)N * H * 4);
    float* a_d    = (float*)alloc((size_t)N * H * 4);
    float* m_ns   = (float*)alloc((size_t)N * H * 4);
    float* s_ns   = (float*)alloc((size_t)N * H * 4);
    float* alpha  = (float*)alloc((size_t)NE * H * 4);
    float* dinv   = (float*)alloc((size_t)N * 4);
    float* gfeat  = (float*)alloc((size_t)G * 1560 * 4);
    float* Mbuf   = (float*)alloc((size_t)G * 26 * 256 * 4);
    int* deg       = (int*)alloc((size_t)N * 4);
    int* row_start = (int*)alloc((size_t)(N + 1) * 4);
    int* fill_cnt  = (int*)alloc((size_t)N * 4);
    int* edge_list = (int*)alloc((size_t)NE * 4);
    int* gcnt      = (int*)alloc((size_t)G * 4);
    int* gstart    = (int*)alloc((size_t)(G + 1) * 4);

    if (off > ws_size) {
        fprintf(stderr, "kernel_launch: workspace too small: need %zu have %zu\n", off, ws_size);
        return;
    }

    hipMemsetAsync(deg, 0, (size_t)N * 4, stream);
    hipMemsetAsync(fill_cnt, 0, (size_t)N * 4, stream);
    hipMemsetAsync(gcnt, 0, (size_t)G * 4, stream);
    hipMemsetAsync(g1_b, 0, (size_t)G * 1504 * 2, stream);  // K-pad cols must be 0

    dim3 tb(32, 8);

    // ---- weight transposes + input cast (all independent, run upfront) ----
    k_cast_pad_x<<<CDIV(N * KP_GAT, 256), 256, 0, stream>>>(x, xb);
    k_transpose_cast_t<<<dim3(CDIV(KP_GAT,32), CDIV(C,32)), tb, 0, stream>>>(W_gat, Wgat_t, F, C, KP_GAT);
    k_transpose_cast_t<<<dim3(CDIV(KP_GCN,32), CDIV(C,32)), tb, 0, stream>>>(W_gcn, Wgcn_t, C, C, KP_GCN);
    k_transpose_cast_t<<<dim3(CDIV(1568,32), CDIV(1500,32)), tb, 0, stream>>>(W_fcg1, Wfcg1_t, 1560, 1500, 1568);
    k_transpose_cast_t<<<dim3(CDIV(1504,32), CDIV(128,32)),  tb, 0, stream>>>(W_fcg2, Wfcg2_t, 1500, 128, 1504);
    k_transpose_cast_t<<<dim3(CDIV(3872,32), CDIV(128,32)),  tb, 0, stream>>>(W_fc2xt, Wfc2xt_t, 3872, 128, 3872);
    k_transpose_cast_t<<<dim3(CDIV(544,32),  CDIV(128,32)),  tb, 0, stream>>>(W_fc1xt, Wfc1xt_t, 544, 128, 544);
    k_transpose_cast_t<<<dim3(CDIV(384,32),  CDIV(1024,32)), tb, 0, stream>>>(W_fc1, Wfc1_t, 384, 1024, 384);
    k_transpose_cast_t<<<dim3(CDIV(1024,32), CDIV(512,32)),  tb, 0, stream>>>(W_fc2, Wfc2_t, 1024, 512, 1024);

    // ---- attention logits ----
    k_Vsd<<<CDIV(F * H, 256), 256, 0, stream>>>(W_gat, att_src, att_dst, V_s, V_d);
    k_ascores<<<CDIV(N, 256), 256, 0, stream>>>(x, V_s, V_d, a_s, a_d);

    // ---- CSR + graph ranges ----
    count_deg<<<CDIV(NE, 256), 256, 0, stream>>>(ei, deg);
    scan_int<<<1, 1024, 0, stream>>>(deg, row_start, N);
    fill_csr<<<CDIV(NE, 256), 256, 0, stream>>>(ei, row_start, fill_cnt, edge_list);
    k_graph_cnt<<<CDIV(N, 256), 256, 0, stream>>>(batch, gcnt);
    scan_int<<<1, 1024, 0, stream>>>(gcnt, gstart, G);

    // ---- softmax ----
    k_softmax_stats<<<CDIV(N * H, 256), 256, 0, stream>>>(ei, row_start, edge_list, a_s, a_d, m_ns, s_ns);
    k_alpha<<<CDIV(NE * H, 256), 256, 0, stream>>>(ei, a_s, a_d, m_ns, s_ns, alpha);
    k_dinv<<<CDIV(N, 256), 256, 0, stream>>>(deg, dinv);

    // ---- GAT ----
    {
        dim3 grid(CDIV(N, 128), CDIV(C, 128));
        gemm_mfma<<<grid, 256, 0, stream>>>(xb, Wgat_t, h_buf, nullptr, 0,
                                            N, C, KP_GAT / 32, KP_GAT, KP_GAT, C);
    }
    gat_agg_full<<<N, 256, 0, stream>>>(h_buf, alpha, ei, row_start, edge_list, b_gat, gat_out);

    // ---- GCN ----
    {
        dim3 grid(CDIV(N, 128), CDIV(C, 128));
        gemm_mfma<<<grid, 256, 0, stream>>>(gat_out, Wgcn_t, h_buf, nullptr, 0,
                                            N, C, KP_GCN / 32, KP_GCN, KP_GCN, C);
    }
    unsigned short* gcn_out = gat_out;   // dead after GEMM, reuse
    gcn_agg_full<<<N, 256, 0, stream>>>(h_buf, dinv, ei, row_start, edge_list, b_gcn, gcn_out);
    {
        dim3 pgrid(G, CDIV(C, 64));
        k_pool_full<<<pgrid, 64, 0, stream>>>(gcn_out, gstart, gfeat);
    }

    // ---- graph FC branch (bf16 MFMA) ----
    k_cast_pad<<<CDIV(G * 1568, 256), 256, 0, stream>>>(gfeat, gfeat_b, G, 1560, 1568);
    gemm_mfma<<<dim3(1, CDIV(1500,128)), 256, 0, stream>>>(gfeat_b, Wfcg1_t, g1_b, b_fcg1, 1,
                                                           G, 1500, 1568/32, 1568, 1568, 1504);
    gemm_mfma<<<dim3(1, 1), 256, 0, stream>>>(g1_b, Wfcg2_t, xc_b, b_fcg2, 0,
                                              G, 128, 1504/32, 1504, 1504, 384);

    // ---- protein branch 2 ----
    k_build_M<<<G, 256, 0, stream>>>(t2, Wc2, Mbuf);
    k_conv2<<<CDIV(G * 3872, 256), 256, 0, stream>>>(Mbuf, emb, bc2, xt2c_b);
    gemm_mfma<<<dim3(1, 1), 256, 0, stream>>>(xt2c_b, Wfc2xt_t, xc_b + 256, b_fc2xt, 0,
                                              G, 128, 3872/32, 3872, 3872, 384);

    // ---- protein branch 1 ----
    k_conv1<<<CDIV(G * 544, 256), 256, 0, stream>>>(t1, Wc1, bc1, xt1c_b);
    gemm_mfma<<<dim3(1, 1), 256, 0, stream>>>(xt1c_b, Wfc1xt_t, xc_b + 128, b_fc1xt, 0,
                                              G, 128, 544/32, 544, 544, 384);

    // ---- head ----
    gemm_mfma<<<dim3(1, CDIV(1024,128)), 256, 0, stream>>>(xc_b, Wfc1_t, f1_b, b_fc1, 1,
                                                           G, 1024, 384/32, 384, 384, 1024);
    gemm_mfma<<<dim3(1, CDIV(512,128)), 256, 0, stream>>>(f1_b, Wfc2_t, f2_b, b_fc2, 1,
                                                          G, 512, 1024/32, 1024, 1024, 512);
    k_fc_out<<<G, 64, 0, stream>>>(f2_b, W_out, b_out, (float*)d_out);
}

// Round 6
// 1328.338 us; speedup vs baseline: 4.2002x; 1.1764x over previous
//
#include <hip/hip_runtime.h>
#include <cstdio>
#include <cstdint>

#define CDIV(a,b) (((a)+(b)-1)/(b))

static const int N   = 50000;   // nodes
static const int NE0 = 150000;  // edges w/o self loops
static const int NE  = 200000;  // edges with self loops
static const int H   = 10;      // heads
static const int F   = 78;      // per-head features
static const int C   = 780;     // H*F
static const int G   = 128;     // graphs
static const int KP_GAT = 96;   // 78 padded to 3*32
static const int CP1 = 800;     // h1/gat_out cols: 10 heads x 80 (per-head pad 78->80)
static const int CP2 = 784;     // h2/gcn_out cols: 780 padded to 98*8

typedef __attribute__((ext_vector_type(8))) short bf16x8;
typedef __attribute__((ext_vector_type(4))) float f32x4;
typedef __attribute__((ext_vector_type(8))) unsigned short us8;

__device__ __forceinline__ float bf2f(unsigned short u) {
    return __uint_as_float(((unsigned int)u) << 16);
}
__device__ __forceinline__ unsigned short f2bf(float f) {
    unsigned int u = __float_as_uint(f);
    u = (u + 0x7fff + ((u >> 16) & 1)) >> 16;   // RNE
    return (unsigned short)u;
}

// ---------------------------------------------------------------------------
// bf16 MFMA GEMM: C[M,Nn] = A[M,K] @ B[K,Nn] (+bias, optional relu).
// A bf16 [M][lda], Bt bf16 [Nn][ldb] (B transposed), out bf16 [M][ldc].
// Block 256 thr = 4 waves (2x2), tile 128x128, BK=32.
// ---------------------------------------------------------------------------
__global__ __launch_bounds__(256)
void gemm_mfma(const unsigned short* __restrict__ A,
               const unsigned short* __restrict__ Bt,
               unsigned short* __restrict__ Cb,
               const float* __restrict__ bias, int relu,
               int M, int Nn, int kSteps, int lda, int ldb, int ldc)
{
    __shared__ unsigned short As[128][40];   // +8 pad: 2-way bank pattern (free)
    __shared__ unsigned short Bs[128][40];
    const int tid = threadIdx.x;
    const int lane = tid & 63;
    const int wave = tid >> 6;
    const int wm = (wave >> 1) * 64, wn = (wave & 1) * 64;
    const int bm = blockIdx.x * 128, bn = blockIdx.y * 128;

    f32x4 acc[4][4] = {};

    const int lrow = tid >> 2;        // 0..63
    const int lk   = (tid & 3) * 8;   // 0,8,16,24
    const int mrow = lane & 15, quad = lane >> 4;

    for (int ks = 0; ks < kSteps; ks++) {
        const int k0 = ks * 32;
        {   // clamped loads; garbage rows discarded by store guard
            int r0 = min(bm + lrow, M - 1);
            int r1 = min(bm + lrow + 64, M - 1);
            *(us8*)&As[lrow][lk]      = *(const us8*)&A[(size_t)r0 * lda + k0 + lk];
            *(us8*)&As[lrow + 64][lk] = *(const us8*)&A[(size_t)r1 * lda + k0 + lk];
            int n0 = min(bn + lrow, Nn - 1);
            int n1 = min(bn + lrow + 64, Nn - 1);
            *(us8*)&Bs[lrow][lk]      = *(const us8*)&Bt[(size_t)n0 * ldb + k0 + lk];
            *(us8*)&Bs[lrow + 64][lk] = *(const us8*)&Bt[(size_t)n1 * ldb + k0 + lk];
        }
        __syncthreads();
        bf16x8 af[4], bfr[4];
#pragma unroll
        for (int i = 0; i < 4; i++) {
            af[i]  = *(const bf16x8*)&As[wm + i * 16 + mrow][quad * 8];
            bfr[i] = *(const bf16x8*)&Bs[wn + i * 16 + mrow][quad * 8];
        }
#pragma unroll
        for (int i = 0; i < 4; i++)
#pragma unroll
            for (int j = 0; j < 4; j++)
                acc[i][j] = __builtin_amdgcn_mfma_f32_16x16x32_bf16(af[i], bfr[j], acc[i][j], 0, 0, 0);
        __syncthreads();
    }

    // epilogue: C/D layout col=lane&15, row=quad*4+reg  [m89-verified]
#pragma unroll
    for (int i = 0; i < 4; i++) {
#pragma unroll
        for (int j = 0; j < 4; j++) {
            int col = bn + wn + j * 16 + mrow;
            if (col >= Nn) continue;
            float bv = bias ? bias[col] : 0.f;
#pragma unroll
            for (int r = 0; r < 4; r++) {
                int row = bm + wm + i * 16 + quad * 4 + r;
                if (row >= M) continue;
                float v = acc[i][j][r] + bv;
                if (relu) v = fmaxf(v, 0.f);
                Cb[(size_t)row * ldc + col] = f2bf(v);
            }
        }
    }
}

// final [G,512]bf16 @ [512,1] + b -> d_out; one block (64 lanes) per graph
__global__ void k_fc_out(const unsigned short* __restrict__ f2, const float* __restrict__ W,
                         const float* __restrict__ b, float* __restrict__ out)
{
    int g = blockIdx.x, lane = threadIdx.x;
    float acc = 0.f;
    for (int k = lane; k < 512; k += 64) acc += bf2f(f2[g * 512 + k]) * W[k];
#pragma unroll
    for (int off = 32; off > 0; off >>= 1) acc += __shfl_down(acc, off, 64);
    if (lane == 0) out[g] = acc + b[0];
}

// ---------------------------------------------------------------------------
// casts / weight builds
// ---------------------------------------------------------------------------
__global__ void k_cast_pad_x(const float* __restrict__ x, unsigned short* __restrict__ xb)
{
    int idx = blockIdx.x * blockDim.x + threadIdx.x;
    if (idx >= N * KP_GAT) return;
    int n = idx / KP_GAT, k = idx % KP_GAT;
    float v = (k < F) ? x[(size_t)n * F + k] : 0.f;
    xb[idx] = f2bf(v);
}

// generic fp32 [M][K] -> bf16 [M][Kpad] zero-padded
__global__ void k_cast_pad(const float* __restrict__ src, unsigned short* __restrict__ dst,
                           int M, int K, int Kpad)
{
    int idx = blockIdx.x * blockDim.x + threadIdx.x;
    if (idx >= M * Kpad) return;
    int m = idx / Kpad, k = idx % Kpad;
    dst[idx] = f2bf((k < K) ? src[(size_t)m * K + k] : 0.f);
}

// LDS-tiled transpose-cast: W[K][Nn] fp32 -> Wt[Nn][Kpad] bf16 (pads zeroed).
__global__ void k_transpose_cast_t(const float* __restrict__ W, unsigned short* __restrict__ Wt,
                                   int K, int Nn, int Kpad)
{
    __shared__ float tile[32][33];
    int k0 = blockIdx.x * 32, n0 = blockIdx.y * 32;
    int tx = threadIdx.x, ty = threadIdx.y;
    for (int r = ty; r < 32; r += 8) {
        int k = k0 + r, n = n0 + tx;
        tile[r][tx] = (k < K && n < Nn) ? W[(size_t)k * Nn + n] : 0.f;
    }
    __syncthreads();
    for (int r = ty; r < 32; r += 8) {
        int n = n0 + r, k = k0 + tx;
        if (n < Nn && k < Kpad) Wt[(size_t)n * Kpad + k] = f2bf(tile[tx][r]);
    }
}

// Wgat_t[n][k], n in [0,800): head h=n/80, f=n%80; col h*78+f of W_gat; 0 pads.
__global__ void k_build_Wgat_t(const float* __restrict__ W_gat, unsigned short* __restrict__ Wt)
{
    int idx = blockIdx.x * blockDim.x + threadIdx.x;
    if (idx >= KP_GAT * CP1) return;
    int k = idx / CP1, n = idx % CP1;          // k-major: coalesced W reads
    int h = n / 80, f = n % 80;
    float v = (k < F && f < F) ? W_gat[(size_t)k * C + h * F + f] : 0.f;
    Wt[(size_t)n * KP_GAT + k] = f2bf(v);
}

// Wgcn_t[n][kpad], n in [0,784): out channel (0 for n>=780);
// kpad = h*80+f maps W_gcn row h*78+f; pad kpad rows pre-zeroed by memset.
__global__ void k_build_Wgcn_t(const float* __restrict__ W_gcn, unsigned short* __restrict__ Wt)
{
    int idx = blockIdx.x * blockDim.x + threadIdx.x;
    if (idx >= C * CP2) return;
    int ko = idx / CP2, n = idx % CP2;         // ko-major: coalesced W reads
    int h = ko / F, f = ko % F;
    float v = (n < C) ? W_gcn[(size_t)ko * C + n] : 0.f;
    Wt[(size_t)n * CP1 + h * 80 + f] = f2bf(v);
}

// ---------------------------------------------------------------------------
// attention logits
// ---------------------------------------------------------------------------
__global__ void k_Vsd(const float* __restrict__ W_gat, const float* __restrict__ att_src,
                      const float* __restrict__ att_dst, float* __restrict__ V_s,
                      float* __restrict__ V_d)
{
    int idx = blockIdx.x * blockDim.x + threadIdx.x;
    if (idx >= F * H) return;
    int k = idx / H, h = idx % H;
    const float* wr = W_gat + (size_t)k * C + h * F;
    const float* as = att_src + h * F;
    const float* ad = att_dst + h * F;
    float s = 0.f, d = 0.f;
    for (int f = 0; f < F; f++) { float w = wr[f]; s += w * as[f]; d += w * ad[f]; }
    V_s[idx] = s; V_d[idx] = d;
}

__global__ void k_ascores(const float* __restrict__ x, const float* __restrict__ V_s,
                          const float* __restrict__ V_d, float* __restrict__ a_s,
                          float* __restrict__ a_d)
{
    __shared__ float Vs[F * H], Vd[F * H];
    int t = threadIdx.x;
    for (int i = t; i < F * H; i += 256) { Vs[i] = V_s[i]; Vd[i] = V_d[i]; }
    __syncthreads();
    int n = blockIdx.x * 256 + t;
    if (n >= N) return;
    const float* xr = x + (size_t)n * F;
    float accs[H] = {}, accd[H] = {};
    for (int k = 0; k < F; k++) {
        float xv = xr[k];
        const float* vs = &Vs[k * H];
        const float* vd = &Vd[k * H];
#pragma unroll
        for (int h = 0; h < H; h++) { accs[h] += xv * vs[h]; accd[h] += xv * vd[h]; }
    }
    for (int h = 0; h < H; h++) { a_s[n * H + h] = accs[h]; a_d[n * H + h] = accd[h]; }
}

// ---------------------------------------------------------------------------
// CSR build (self-loops appended; srcs/dsts stored directly)
// ---------------------------------------------------------------------------
__global__ void count_deg(const int* __restrict__ ei, int* __restrict__ deg)
{
    int e = blockIdx.x * blockDim.x + threadIdx.x;
    if (e >= NE) return;
    int d = (e < NE0) ? ei[NE0 + e] : (e - NE0);
    atomicAdd(&deg[d], 1);
}

__global__ void scan_int(const int* __restrict__ cnt, int* __restrict__ row_start, int n)
{
    __shared__ int partial[1024];
    int tid = threadIdx.x;
    int per = CDIV(n, 1024);
    int start = tid * per, end = min(start + per, n);
    int sum = 0;
    for (int i = start; i < end; i++) sum += cnt[i];
    partial[tid] = sum;
    __syncthreads();
    for (int off = 1; off < 1024; off *= 2) {
        int v = (tid >= off) ? partial[tid - off] : 0;
        __syncthreads();
        partial[tid] += v;
        __syncthreads();
    }
    int base = (tid > 0) ? partial[tid - 1] : 0;
    for (int i = start; i < end; i++) { row_start[i] = base; base += cnt[i]; }
    if (tid == 1023) row_start[n] = base;
}

__global__ void fill_csr(const int* __restrict__ ei, const int* __restrict__ row_start,
                         int* __restrict__ fill_cnt, int* __restrict__ srcs,
                         int* __restrict__ dsts)
{
    int e = blockIdx.x * blockDim.x + threadIdx.x;
    if (e >= NE) return;
    int sr = (e < NE0) ? ei[e] : (e - NE0);
    int d  = (e < NE0) ? ei[NE0 + e] : (e - NE0);
    int pos = row_start[d] + atomicAdd(&fill_cnt[d], 1);
    srcs[pos] = sr;
    dsts[pos] = d;
}

__global__ void k_graph_cnt(const int* __restrict__ batch, int* __restrict__ gcnt)
{
    int n = blockIdx.x * blockDim.x + threadIdx.x;
    if (n >= N) return;
    atomicAdd(&gcnt[batch[n]], 1);
}

// ---------------------------------------------------------------------------
// GAT softmax: stage leaky logits once (edge-parallel), then fused stats+alpha
// ---------------------------------------------------------------------------
__global__ void k_edge_ev(const int* __restrict__ srcs, const int* __restrict__ dsts,
                          const float* __restrict__ a_s, const float* __restrict__ a_d,
                          float* __restrict__ evb)
{
    int i = blockIdx.x * blockDim.x + threadIdx.x;
    if (i >= NE) return;
    int sr = srcs[i], ds = dsts[i];
    const float* as = a_s + sr * H;
    const float* ad = a_d + ds * H;
    float* ev = evb + (size_t)i * H;
#pragma unroll
    for (int h = 0; h < H; h++) {
        float e = as[h] + ad[h];
        ev[h] = (e > 0.f) ? e : 0.2f * e;
    }
}

// per (node, head): online max/sum over CSR run, rewrite evb in place as alpha
__global__ void k_softmax_alpha(const int* __restrict__ row_start, float* __restrict__ evb)
{
    int idx = blockIdx.x * blockDim.x + threadIdx.x;
    if (idx >= N * H) return;
    int n = idx / H, h = idx % H;
    int rs = row_start[n], re = row_start[n + 1];
    float m = -INFINITY, s = 0.f;
    for (int i = rs; i < re; i++) {
        float ev = evb[(size_t)i * H + h];
        if (ev <= m) {
            s += expf(ev - m);
        } else {
            s = s * expf(m - ev) + 1.f;
            m = ev;
        }
    }
    float inv = 1.f / (s + 1e-16f);
    for (int i = rs; i < re; i++) {
        float ev = evb[(size_t)i * H + h];
        evb[(size_t)i * H + h] = expf(ev - m) * inv;
    }
}

// ---------------------------------------------------------------------------
// GAT aggregation: h1 bf16 [N][800] head-padded -> gat_out bf16 [N][800].
// Block 128 thr, lane owns 8 contiguous cols (one us8), h = c/80.
// ---------------------------------------------------------------------------
__global__ __launch_bounds__(128)
void gat_agg(const unsigned short* __restrict__ h1, const float* __restrict__ alpha,
             const int* __restrict__ srcs, const int* __restrict__ row_start,
             const float* __restrict__ b_gat, unsigned short* __restrict__ out)
{
    int n = blockIdx.x;
    int c = threadIdx.x * 8;
    if (c >= CP1) return;
    int h = c / 80, f0 = c % 80;
    int rs = row_start[n], re = row_start[n + 1];
    float acc[8] = {};
    for (int i = rs; i < re; i++) {
        int sr = srcs[i];
        float a = alpha[(size_t)i * H + h];
        us8 v = *(const us8*)&h1[(size_t)sr * CP1 + c];
#pragma unroll
        for (int j = 0; j < 8; j++) acc[j] += a * bf2f(v[j]);
    }
    us8 o;
#pragma unroll
    for (int j = 0; j < 8; j++) {
        int f = f0 + j;
        float r = (f < F) ? fmaxf(acc[j] + b_gat[h * F + f], 0.f) : 0.f;
        o[j] = f2bf(r);
    }
    *(us8*)&out[(size_t)n * CP1 + c] = o;
}

__global__ void k_dinv(const int* __restrict__ deg, float* __restrict__ dinv)
{
    int n = blockIdx.x * blockDim.x + threadIdx.x;
    if (n >= N) return;
    int d = deg[n];
    dinv[n] = (d > 0) ? 1.f / sqrtf((float)d) : 0.f;
}

// GCN aggregation: h2 bf16 [N][784] -> gcn_out bf16 [N][784]
__global__ __launch_bounds__(128)
void gcn_agg(const unsigned short* __restrict__ h2, const float* __restrict__ dinv,
             const int* __restrict__ srcs, const int* __restrict__ row_start,
             const float* __restrict__ b_gcn, unsigned short* __restrict__ out)
{
    int n = blockIdx.x;
    int c = threadIdx.x * 8;
    if (c >= CP2) return;
    float dn = dinv[n];
    int rs = row_start[n], re = row_start[n + 1];
    float acc[8] = {};
    for (int i = rs; i < re; i++) {
        int sr = srcs[i];
        float d = dinv[sr];
        us8 v = *(const us8*)&h2[(size_t)sr * CP2 + c];
#pragma unroll
        for (int j = 0; j < 8; j++) acc[j] += d * bf2f(v[j]);
    }
    us8 o;
#pragma unroll
    for (int j = 0; j < 8; j++) {
        int col = c + j;
        float r = (col < C) ? fmaxf(acc[j] * dn + b_gcn[col], 0.f) : 0.f;
        o[j] = f2bf(r);
    }
    *(us8*)&out[(size_t)n * CP2 + c] = o;
}

// max+mean pool: block per graph, 128 thr, lane owns 8 cols
__global__ __launch_bounds__(128)
void k_pool(const unsigned short* __restrict__ hh, const int* __restrict__ gstart,
            float* __restrict__ gfeat)
{
    int g = blockIdx.x;
    int c = threadIdx.x * 8;
    if (c >= CP2) return;
    int s = gstart[g], e = gstart[g + 1];
    float mx[8] = {}, sm[8] = {};
    for (int n = s; n < e; n++) {
        us8 v = *(const us8*)&hh[(size_t)n * CP2 + c];
#pragma unroll
        for (int j = 0; j < 8; j++) { float f = bf2f(v[j]); mx[j] = fmaxf(mx[j], f); sm[j] += f; }
    }
    float cnt = fmaxf((float)(e - s), 1.f);
#pragma unroll
    for (int j = 0; j < 8; j++) {
        int col = c + j;
        if (col < C) {
            gfeat[g * 1560 + col] = mx[j];
            gfeat[g * 1560 + 780 + col] = sm[j] / cnt;
        }
    }
}

// ---------------------------------------------------------------------------
// protein branches
// ---------------------------------------------------------------------------
__global__ void k_build_M(const int* __restrict__ t2, const float* __restrict__ Wc2,
                          float* __restrict__ Mbuf)
{
    __shared__ float Ml[26 * 256];
    int b = blockIdx.x, t = threadIdx.x;
    for (int j = t; j < 26 * 256; j += 256) Ml[j] = 0.f;
    __syncthreads();
    int o = t >> 3, k = t & 7;
    const int* tb = t2 + b * 1000;
    for (int cc = 0; cc < 1000; cc++) {
        int tok = tb[cc];
        Ml[tok * 256 + t] += Wc2[o * 8000 + cc * 8 + k];
    }
    __syncthreads();
    float* Mb = Mbuf + (size_t)b * (26 * 256);
    for (int j = t; j < 26 * 256; j += 256) Mb[j] = Ml[j];
}

__global__ void k_conv2(const float* __restrict__ Mbuf, const float* __restrict__ emb,
                        const float* __restrict__ bc2, unsigned short* __restrict__ xt2c)
{
    int idx = blockIdx.x * blockDim.x + threadIdx.x;
    if (idx >= G * 3872) return;
    int b = idx / 3872, r = idx % 3872;
    int o = r / 121, l = r % 121;
    const float* Mb = Mbuf + (size_t)b * (26 * 256);
    float acc = bc2[o];
    for (int t = 0; t < 26; t++) {
        const float* mrow = Mb + t * 256 + o * 8;
        const float* erow = emb + t * 128 + l;
#pragma unroll
        for (int k = 0; k < 8; k++) acc += mrow[k] * erow[k];
    }
    xt2c[idx] = f2bf(acc);
}

__global__ void k_conv1(const float* __restrict__ t1, const float* __restrict__ Wc1,
                        const float* __restrict__ bc1, unsigned short* __restrict__ xt1c)
{
    int idx = blockIdx.x * blockDim.x + threadIdx.x;
    if (idx >= G * 544) return;
    int b = idx / 544, r = idx % 544;
    int o = r / 17, l = r % 17;
    float acc = bc1[o];
    const float* xb = t1 + b * 480;
    const float* wo = Wc1 + o * 160;
    for (int cc = 0; cc < 20; cc++) {
        const float* xr = xb + cc * 24 + l;
        const float* wr = wo + cc * 8;
#pragma unroll
        for (int k = 0; k < 8; k++) acc += xr[k] * wr[k];
    }
    xt1c[idx] = f2bf(acc);
}

// ---------------------------------------------------------------------------
extern "C" void kernel_launch(void* const* d_in, const int* in_sizes, int n_in,
                              void* d_out, int out_size, void* d_ws, size_t ws_size,
                              hipStream_t stream)
{
    const float* x       = (const float*)d_in[0];
    const int*   ei      = (const int*)  d_in[1];
    const int*   batch   = (const int*)  d_in[2];
    const float* t1      = (const float*)d_in[3];
    const int*   t2      = (const int*)  d_in[4];
    const float* W_gat   = (const float*)d_in[5];
    const float* att_src = (const float*)d_in[6];
    const float* att_dst = (const float*)d_in[7];
    const float* b_gat   = (const float*)d_in[8];
    const float* W_gcn   = (const float*)d_in[9];
    const float* b_gcn   = (const float*)d_in[10];
    const float* W_fcg1  = (const float*)d_in[11];
    const float* b_fcg1  = (const float*)d_in[12];
    const float* W_fcg2  = (const float*)d_in[13];
    const float* b_fcg2  = (const float*)d_in[14];
    const float* emb     = (const float*)d_in[15];
    const float* Wc2     = (const float*)d_in[16];
    const float* bc2     = (const float*)d_in[17];
    const float* W_fc2xt = (const float*)d_in[18];
    const float* b_fc2xt = (const float*)d_in[19];
    const float* Wc1     = (const float*)d_in[20];
    const float* bc1     = (const float*)d_in[21];
    const float* W_fc1xt = (const float*)d_in[22];
    const float* b_fc1xt = (const float*)d_in[23];
    const float* W_fc1   = (const float*)d_in[24];
    const float* b_fc1   = (const float*)d_in[25];
    const float* W_fc2   = (const float*)d_in[26];
    const float* b_fc2   = (const float*)d_in[27];
    const float* W_out   = (const float*)d_in[28];
    const float* b_out   = (const float*)d_in[29];

    char* wsb = (char*)d_ws;
    size_t off = 0;
    auto alloc = [&](size_t bytes) -> char* {
        char* p = wsb + off;
        off += (bytes + 255) & ~(size_t)255;
        return p;
    };

    unsigned short* h_buf   = (unsigned short*)alloc((size_t)N * CP1 * 2);  // h1 [N][800]; then h2 [N][784]
    unsigned short* gat_out = (unsigned short*)alloc((size_t)N * CP1 * 2);  // [N][800]; reused as gcn_out [N][784]
    unsigned short* xb      = (unsigned short*)alloc((size_t)N * KP_GAT * 2);
    unsigned short* Wgat_t  = (unsigned short*)alloc((size_t)CP1 * KP_GAT * 2);
    unsigned short* Wgcn_t  = (unsigned short*)alloc((size_t)CP2 * CP1 * 2);
    // FC tail bf16 weights (transposed) + activations
    unsigned short* Wfcg1_t  = (unsigned short*)alloc((size_t)1500 * 1568 * 2);
    unsigned short* Wfcg2_t  = (unsigned short*)alloc((size_t)128 * 1504 * 2);
    unsigned short* Wfc2xt_t = (unsigned short*)alloc((size_t)128 * 3872 * 2);
    unsigned short* Wfc1xt_t = (unsigned short*)alloc((size_t)128 * 544 * 2);
    unsigned short* Wfc1_t   = (unsigned short*)alloc((size_t)1024 * 384 * 2);
    unsigned short* Wfc2_t   = (unsigned short*)alloc((size_t)512 * 1024 * 2);
    unsigned short* gfeat_b  = (unsigned short*)alloc((size_t)G * 1568 * 2);
    unsigned short* g1_b     = (unsigned short*)alloc((size_t)G * 1504 * 2);
    unsigned short* xt2c_b   = (unsigned short*)alloc((size_t)G * 3872 * 2);
    unsigned short* xt1c_b   = (unsigned short*)alloc((size_t)G * 544 * 2);
    unsigned short* xc_b     = (unsigned short*)alloc((size_t)G * 384 * 2);
    unsigned short* f1_b     = (unsigned short*)alloc((size_t)G * 1024 * 2);
    unsigned short* f2_b     = (unsigned short*)alloc((size_t)G * 512 * 2);
    float* V_s    = (float*)alloc((size_t)F * H * 4);
    float* V_d    = (float*)alloc((size_t)F * H * 4);
    float* a_s    = (float*)alloc((size_t)N * H * 4);
    float* a_d    = (float*)alloc((size_t)N * H * 4);
    float* evb    = (float*)alloc((size_t)NE * H * 4);   // ev -> alpha in place
    float* dinv   = (float*)alloc((size_t)N * 4);
    float* gfeat  = (float*)alloc((size_t)G * 1560 * 4);
    float* Mbuf   = (float*)alloc((size_t)G * 26 * 256 * 4);
    int* deg       = (int*)alloc((size_t)N * 4);
    int* row_start = (int*)alloc((size_t)(N + 1) * 4);
    int* fill_cnt  = (int*)alloc((size_t)N * 4);
    int* srcs      = (int*)alloc((size_t)NE * 4);
    int* dsts      = (int*)alloc((size_t)NE * 4);
    int* gcnt      = (int*)alloc((size_t)G * 4);
    int* gstart    = (int*)alloc((size_t)(G + 1) * 4);

    if (off > ws_size) {
        fprintf(stderr, "kernel_launch: workspace too small: need %zu have %zu\n", off, ws_size);
        return;
    }

    hipMemsetAsync(deg, 0, (size_t)N * 4, stream);
    hipMemsetAsync(fill_cnt, 0, (size_t)N * 4, stream);
    hipMemsetAsync(gcnt, 0, (size_t)G * 4, stream);
    hipMemsetAsync(g1_b, 0, (size_t)G * 1504 * 2, stream);      // K-pad cols must be 0
    hipMemsetAsync(Wgcn_t, 0, (size_t)CP2 * CP1 * 2, stream);   // pad k rows must be 0

    dim3 tb(32, 8);

    // ---- weight builds + input cast ----
    k_cast_pad_x<<<CDIV(N * KP_GAT, 256), 256, 0, stream>>>(x, xb);
    k_build_Wgat_t<<<CDIV(KP_GAT * CP1, 256), 256, 0, stream>>>(W_gat, Wgat_t);
    k_build_Wgcn_t<<<CDIV(C * CP2, 256), 256, 0, stream>>>(W_gcn, Wgcn_t);
    k_transpose_cast_t<<<dim3(CDIV(1568,32), CDIV(1500,32)), tb, 0, stream>>>(W_fcg1, Wfcg1_t, 1560, 1500, 1568);
    k_transpose_cast_t<<<dim3(CDIV(1504,32), CDIV(128,32)),  tb, 0, stream>>>(W_fcg2, Wfcg2_t, 1500, 128, 1504);
    k_transpose_cast_t<<<dim3(CDIV(3872,32), CDIV(128,32)),  tb, 0, stream>>>(W_fc2xt, Wfc2xt_t, 3872, 128, 3872);
    k_transpose_cast_t<<<dim3(CDIV(544,32),  CDIV(128,32)),  tb, 0, stream>>>(W_fc1xt, Wfc1xt_t, 544, 128, 544);
    k_transpose_cast_t<<<dim3(CDIV(384,32),  CDIV(1024,32)), tb, 0, stream>>>(W_fc1, Wfc1_t, 384, 1024, 384);
    k_transpose_cast_t<<<dim3(CDIV(1024,32), CDIV(512,32)),  tb, 0, stream>>>(W_fc2, Wfc2_t, 1024, 512, 1024);

    // ---- attention logits ----
    k_Vsd<<<CDIV(F * H, 256), 256, 0, stream>>>(W_gat, att_src, att_dst, V_s, V_d);
    k_ascores<<<CDIV(N, 256), 256, 0, stream>>>(x, V_s, V_d, a_s, a_d);

    // ---- CSR + graph ranges ----
    count_deg<<<CDIV(NE, 256), 256, 0, stream>>>(ei, deg);
    scan_int<<<1, 1024, 0, stream>>>(deg, row_start, N);
    fill_csr<<<CDIV(NE, 256), 256, 0, stream>>>(ei, row_start, fill_cnt, srcs, dsts);
    k_graph_cnt<<<CDIV(N, 256), 256, 0, stream>>>(batch, gcnt);
    scan_int<<<1, 1024, 0, stream>>>(gcnt, gstart, G);

    // ---- softmax (staged ev, fused stats+alpha in place) ----
    k_edge_ev<<<CDIV(NE, 256), 256, 0, stream>>>(srcs, dsts, a_s, a_d, evb);
    k_softmax_alpha<<<CDIV(N * H, 256), 256, 0, stream>>>(row_start, evb);
    k_dinv<<<CDIV(N, 256), 256, 0, stream>>>(deg, dinv);

    // ---- GAT: h1 = x @ W_gat (head-padded 800-col output) ----
    {
        dim3 grid(CDIV(N, 128), CDIV(CP1, 128));
        gemm_mfma<<<grid, 256, 0, stream>>>(xb, Wgat_t, h_buf, nullptr, 0,
                                            N, CP1, KP_GAT / 32, KP_GAT, KP_GAT, CP1);
    }
    gat_agg<<<N, 128, 0, stream>>>(h_buf, evb, srcs, row_start, b_gat, gat_out);

    // ---- GCN: h2 = gat_out @ W_gcn (784-col output) ----
    {
        dim3 grid(CDIV(N, 128), CDIV(CP2, 128));
        gemm_mfma<<<grid, 256, 0, stream>>>(gat_out, Wgcn_t, h_buf, nullptr, 0,
                                            N, CP2, CP1 / 32, CP1, CP1, CP2);
    }
    unsigned short* gcn_out = gat_out;   // dead after GEMM, reuse
    gcn_agg<<<N, 128, 0, stream>>>(h_buf, dinv, srcs, row_start, b_gcn, gcn_out);
    k_pool<<<G, 128, 0, stream>>>(gcn_out, gstart, gfeat);

    // ---- graph FC branch (bf16 MFMA) ----
    k_cast_pad<<<CDIV(G * 1568, 256), 256, 0, stream>>>(gfeat, gfeat_b, G, 1560, 1568);
    gemm_mfma<<<dim3(1, CDIV(1500,128)), 256, 0, stream>>>(gfeat_b, Wfcg1_t, g1_b, b_fcg1, 1,
                                                           G, 1500, 1568/32, 1568, 1568, 1504);
    gemm_mfma<<<dim3(1, 1), 256, 0, stream>>>(g1_b, Wfcg2_t, xc_b, b_fcg2, 0,
                                              G, 128, 1504/32, 1504, 1504, 384);

    // ---- protein branch 2 ----
    k_build_M<<<G, 256, 0, stream>>>(t2, Wc2, Mbuf);
    k_conv2<<<CDIV(G * 3872, 256), 256, 0, stream>>>(Mbuf, emb, bc2, xt2c_b);
    gemm_mfma<<<dim3(1, 1), 256, 0, stream>>>(xt2c_b, Wfc2xt_t, xc_b + 256, b_fc2xt, 0,
                                              G, 128, 3872/32, 3872, 3872, 384);

    // ---- protein branch 1 ----
    k_conv1<<<CDIV(G * 544, 256), 256, 0, stream>>>(t1, Wc1, bc1, xt1c_b);
    gemm_mfma<<<dim3(1, 1), 256, 0, stream>>>(xt1c_b, Wfc1xt_t, xc_b + 128, b_fc1xt, 0,
                                              G, 128, 544/32, 544, 544, 384);

    // ---- head ----
    gemm_mfma<<<dim3(1, CDIV(1024,128)), 256, 0, stream>>>(xc_b, Wfc1_t, f1_b, b_fc1, 1,
                                                           G, 1024, 384/32, 384, 384, 1024);
    gemm_mfma<<<dim3(1, CDIV(512,128)), 256, 0, stream>>>(f1_b, Wfc2_t, f2_b, b_fc2, 1,
                                                          G, 512, 1024/32, 1024, 1024, 512);
    k_fc_out<<<G, 64, 0, stream>>>(f2_b, W_out, b_out, (float*)d_out);
}